// Round 10
// baseline (195.945 us; speedup 1.0000x reference)
//
#include <hip/hip_runtime.h>
#include <stdint.h>

#define NUMA 3
#define NUMC 80
#define CAP  49152
#define KTOP 400
#define POST 100
#define EQCAP 1024
#define PFCAP 2048
#define KEY0 0x3EE66666u   // __float_as_uint(0.45f): static compact threshold
#define KEYTOP 0x3F800000u // __float_as_uint(1.0f): max possible score key
#define LBUF 1024          // per-block LDS candidate buffer
#define NMASK (KTOP * 7)   // 2800 mask words per image
#define CPB 20             // classes per score_main block
#define NBIN 2048          // coarse hist bins; (key-KEY0)>>13 spans 0..1228

typedef float f32x4 __attribute__((ext_vector_type(4)));

__device__ __forceinline__ float sigmoidf_(float x) { return 1.0f / (1.0f + expf(-x)); }
__device__ __forceinline__ unsigned uminu(unsigned a, unsigned b) { return a < b ? a : b; }

// Conservative raw-logit threshold: x > thr(cf) is NECESSARY for
// sigmoid(x)*cf >= 0.45f (margins 0.449 + 0.01 dwarf float error; the exact
// test still decides membership, so the candidate set is bit-identical).
// cf < 0.45f admits nothing: sc = round(sig*cf) <= cf < 0.45f.
__device__ __forceinline__ float thr_for(float cf) {
    if (!(cf >= 0.45f)) return 3.0e38f;
    float q = 0.449f / cf;             // < 1 guaranteed (cf >= 0.45)
    float r = q / (1.0f - q);
    return logf(r) - 0.01f;
}

// ---------------- main pass: decode + LDS compact + coarse hist ------------
// R10: coarse histogram (R0 structure, measured-free there: only ~0.75% of
// evals hit the LDS atomic) reinstated so topk_sel's warm path can skip its
// full key re-scan. Binning (key-KEY0)>>13 == topk_sel's SH=13/kbase=KEY0.
// Overflow (>LBUF) poisons ccnt -> cold path ignores histN -> exact.
__global__ __launch_bounds__(256) void score_main(
        const float* __restrict__ t0, const float* __restrict__ t1,
        const float* __restrict__ t2,
        unsigned* __restrict__ histN, unsigned* __restrict__ ccnt,
        unsigned* __restrict__ ckey, unsigned* __restrict__ cidx)
{
    __shared__ unsigned lkey[LBUF], lidx[LBUF];
    __shared__ unsigned lh[NBIN];
    __shared__ unsigned lcnt, lbase;
    const int tid = threadIdx.x;
    if (tid == 0) lcnt = 0;
    for (int i = tid; i < NBIN; i += 256) lh[i] = 0;
    __syncthreads();

    const int ba = blockIdx.z;
    const int b = ba / 3, a = ba - 3 * b;
    const int c0 = blockIdx.y * CPB;
    const int cx = blockIdx.x;

    #define LEMIT(SC, IDX) do { \
        unsigned key_ = __float_as_uint(SC); \
        if (key_ >= KEY0) { \
            atomicAdd(&lh[(key_ - KEY0) >> 13], 1u); \
            unsigned pos_ = atomicAdd(&lcnt, 1u); \
            if (pos_ < LBUF) { lkey[pos_] = key_; lidx[pos_] = (IDX); } \
        } \
    } while (0)

    if (cx < 2) {
        const int hw = cx * 256 + tid;
        if (hw < 361) {
            const float* base = t0 + (size_t)(b * 255 + a * 85) * 361;
            float cr = base[4 * 361 + hw];
            const float* p0 = base + (size_t)(5 + c0) * 361 + hw;
            float xv[CPB];
            #pragma unroll
            for (int u = 0; u < CPB; u++) xv[u] = p0[u * 361];
            float cf = sigmoidf_(cr);
            float xt = thr_for(cf);
            unsigned ib = (unsigned)((hw * NUMA + a) * NUMC + c0);
            #pragma unroll
            for (int u = 0; u < CPB; u++)
                if (xv[u] > xt) LEMIT(sigmoidf_(xv[u]) * cf, ib + (unsigned)u);
        }
    } else {
        const float* tip; int vHW, v, candOff;
        if (cx < 4) { tip = t1; vHW = 361;  v = (cx - 2) * 256 + tid; candOff = 86640; }
        else        { tip = t2; vHW = 1444; v = (cx - 4) * 256 + tid; candOff = 433200; }
        if (v < vHW) {
            const f32x4* bp = (const f32x4*)(tip + (size_t)(b * 255 + a * 85) * (size_t)(vHW * 4));
            f32x4 cv = bp[(size_t)4 * vHW + v];
            const f32x4* p0 = bp + (size_t)(5 + c0) * vHW + v;
            f32x4 sv[CPB];
            #pragma unroll
            for (int u = 0; u < CPB; u++) sv[u] = p0[(size_t)u * vHW];
            float cf0 = sigmoidf_(cv[0]), cf1 = sigmoidf_(cv[1]);
            float cf2 = sigmoidf_(cv[2]), cf3 = sigmoidf_(cv[3]);
            float xt0 = thr_for(cf0), xt1 = thr_for(cf1);
            float xt2 = thr_for(cf2), xt3 = thr_for(cf3);
            unsigned ib0 = (unsigned)(candOff + (v * 4 * NUMA + a) * NUMC + c0);
            #pragma unroll
            for (int u = 0; u < CPB; u++) {
                unsigned ib = ib0 + (unsigned)u;
                if (sv[u][0] > xt0) LEMIT(sigmoidf_(sv[u][0]) * cf0, ib);
                if (sv[u][1] > xt1) LEMIT(sigmoidf_(sv[u][1]) * cf1, ib + 240);
                if (sv[u][2] > xt2) LEMIT(sigmoidf_(sv[u][2]) * cf2, ib + 480);
                if (sv[u][3] > xt3) LEMIT(sigmoidf_(sv[u][3]) * cf3, ib + 720);
            }
        }
    }
    #undef LEMIT

    __syncthreads();
    if (tid == 0) {
        unsigned c = lcnt;
        if (c > LBUF) {
            atomicOr(&ccnt[b], 0x80000000u);
            lbase = 0xFFFFFFFFu;
        } else {
            lbase = atomicAdd(&ccnt[b], c);
        }
    }
    __syncthreads();
    unsigned c = uminu(lcnt, (unsigned)LBUF);
    unsigned basep = lbase;
    if (basep != 0xFFFFFFFFu) {
        for (unsigned i = tid; i < c; i += 256) {
            unsigned p = basep + i;
            if (p < CAP) {
                ckey[(size_t)b * CAP + p] = lkey[i];
                cidx[(size_t)b * CAP + p] = lidx[i];
            }
        }
    }
    unsigned* gh = histN + b * NBIN;
    for (int i = tid; i < NBIN; i += 256) {
        unsigned v2 = lh[i];
        if (v2) atomicAdd(&gh[i], v2);
    }
}

// ---------------- wave-parallel rank select over an LDS histogram ----------
__device__ __forceinline__ void wave_select(const unsigned* h, int nbins, unsigned rank,
                                            unsigned* resv, int tid)
{
    if (tid >= 64) return;
    const int lane = tid;
    const int cs = nbins >> 6;
    unsigned v = 0;
    for (int k = 0; k < cs; k++) {
        int off = (k + lane) & (cs - 1);
        v += h[lane * cs + off];
    }
    unsigned S = v;
    #pragma unroll
    for (int o = 1; o < 64; o <<= 1) {
        unsigned t = (unsigned)__shfl_down((int)S, o);
        if (lane + o < 64) S += t;
    }
    unsigned long long bm = __ballot(S >= rank);
    if (bm == 0ull) bm = 1ull;
    int C = 63 - __builtin_clzll(bm);
    unsigned SC = (unsigned)__builtin_amdgcn_readlane((int)S, C);
    unsigned vC = (unsigned)__builtin_amdgcn_readlane((int)v, C);
    unsigned rem = rank - (SC - vC);
    unsigned w = (lane < cs) ? h[C * cs + lane] : 0u;
    unsigned T = w;
    #pragma unroll
    for (int o = 1; o < 64; o <<= 1) {
        unsigned t = (unsigned)__shfl_down((int)T, o);
        if (lane + o < 64) T += t;
    }
    unsigned long long bm2 = __ballot((T >= rem) && (lane < cs));
    if (bm2 == 0ull) bm2 = 1ull;
    int B = 63 - __builtin_clzll(bm2);
    unsigned TB = (unsigned)__builtin_amdgcn_readlane((int)T, B);
    unsigned wB = (unsigned)__builtin_amdgcn_readlane((int)w, B);
    if (lane == 0) {
        resv[0] = (unsigned)(C * cs + B);
        resv[1] = rem - (TB - wB);
    }
}

// ---------------- topk_sel: (cold fb) + select + rank-scatter + decode -----
// R10: warm path loads histN (score_main built it) instead of re-scanning
// all keys; bitonic 512-sort replaced by 1-barrier rank-scatter (strict
// total order on (key desc, idx asc); real items occupy ranks 0..399).
__global__ __launch_bounds__(1024) void topk_sel(
        const float* __restrict__ t0, const float* __restrict__ t1,
        const float* __restrict__ t2,
        const float* __restrict__ anc0, const float* __restrict__ anc1,
        const float* __restrict__ anc2,
        const unsigned* __restrict__ histN, const unsigned* __restrict__ ccnt,
        unsigned* __restrict__ ckey, unsigned* __restrict__ cidx,
        float* __restrict__ dX1, float* __restrict__ dY1,
        float* __restrict__ dX2, float* __restrict__ dY2,
        float* __restrict__ dSC, unsigned* __restrict__ dCID)
{
    const int b = blockIdx.x;
    const int tid = threadIdx.x;
    const int T = 1024;

    __shared__ unsigned hist[4096];
    __shared__ unsigned resv[2];
    __shared__ unsigned selk[512], seli[512];
    __shared__ unsigned sk2[512], si2[512];
    __shared__ unsigned eqi[EQCAP];
    __shared__ unsigned pk[PFCAP], pi[PFCAP];
    __shared__ unsigned cnts[3];   // 0: sel count, 1: eq count, 2: prefilter count
    __shared__ unsigned fcnt;

    unsigned* ck = ckey + (size_t)b * CAP;
    unsigned* ci = cidx + (size_t)b * CAP;
    unsigned nraw = ccnt[b];
    unsigned kbase = KEY0;
    unsigned SH = 13;              // matches score_main's (key-KEY0)>>13

    bool cold = !(nraw >= KTOP && nraw <= CAP);
    if (cold) {
        // ---- COLD fallback: static 0.45 cut invalid for this image ----
        const int NPOS = 3 * (361 + 1444 + 5776);   // 22743 (anchor,pos) pairs
        for (int i = tid; i < 2048; i += T) hist[i] = 0;
        if (tid == 0) fcnt = 0;
        __syncthreads();
        // pass 1: histogram all 1.8M scores by key >> 19
        for (int p = tid; p < NPOS; p += T) {
            const float* tip; int HW, pp;
            if (p < 1083)      { tip = t0; HW = 361;  pp = p; }
            else if (p < 5415) { tip = t1; HW = 1444; pp = p - 1083; }
            else               { tip = t2; HW = 5776; pp = p - 5415; }
            int a = pp / HW, hwl = pp - a * HW;
            const float* base = tip + (size_t)(b * 255 + a * 85) * HW;
            float cf = sigmoidf_(base[4 * HW + hwl]);
            for (int u = 0; u < NUMC; u++) {
                float sc = sigmoidf_(base[(size_t)(5 + u) * HW + hwl]) * cf;
                atomicAdd(&hist[__float_as_uint(sc) >> 19], 1u);
            }
        }
        __syncthreads();
        wave_select(hist, 2048, KTOP, resv, tid);
        __syncthreads();
        unsigned cutkey = resv[0] << 19;
        __syncthreads();
        // pass 2: recompact with the exact bin cut (global ckey/cidx)
        for (int p = tid; p < NPOS; p += T) {
            const float* tip; int HW, pp, candOff;
            if (p < 1083)      { tip = t0; HW = 361;  pp = p;        candOff = 0; }
            else if (p < 5415) { tip = t1; HW = 1444; pp = p - 1083; candOff = 86640; }
            else               { tip = t2; HW = 5776; pp = p - 5415; candOff = 433200; }
            int a = pp / HW, hwl = pp - a * HW;
            const float* base = tip + (size_t)(b * 255 + a * 85) * HW;
            float cf = sigmoidf_(base[4 * HW + hwl]);
            unsigned ib0 = (unsigned)(candOff + (hwl * NUMA + a) * NUMC);
            for (int u = 0; u < NUMC; u++) {
                float sc = sigmoidf_(base[(size_t)(5 + u) * HW + hwl]) * cf;
                unsigned key = __float_as_uint(sc);
                if (key >= cutkey) {
                    unsigned pos = atomicAdd(&fcnt, 1u);
                    if (pos < CAP) { ck[pos] = key; ci[pos] = ib0 + (unsigned)u; }
                }
            }
        }
        __syncthreads();
        nraw = fcnt;
        kbase = cutkey;
        unsigned span = (KEYTOP - kbase) + 1u;
        SH = 0;
        while ((span >> SH) > 2047u) SH++;
    }
    unsigned n = uminu(nraw, (unsigned)CAP);

    // ---- Phase A: coarse hist. Warm: load prebuilt histN. Cold: build. ----
    if (cold) {
        for (int i = tid; i < 2048; i += T) hist[i] = 0;
        __syncthreads();
        unsigned n4 = n >> 2;
        const uint4* ck4 = (const uint4*)ck;
        for (unsigned i = tid; i < n4; i += T) {
            uint4 k = ck4[i];
            atomicAdd(&hist[(k.x - kbase) >> SH], 1u);
            atomicAdd(&hist[(k.y - kbase) >> SH], 1u);
            atomicAdd(&hist[(k.z - kbase) >> SH], 1u);
            atomicAdd(&hist[(k.w - kbase) >> SH], 1u);
        }
        for (unsigned i = (n4 << 2) + tid; i < n; i += T)
            atomicAdd(&hist[(ck[i] - kbase) >> SH], 1u);
    } else {
        for (int i = tid; i < 2048; i += T) hist[i] = histN[b * NBIN + i];
    }
    __syncthreads();
    wave_select(hist, 2048, KTOP, resv, tid);
    __syncthreads();
    unsigned Bf = resv[0];            // rank-400 floor bin
    __syncthreads();

    // ---- Phase B: compact bins >= Bf into LDS (pk/pi) ----
    if (tid == 0) { cnts[0] = 0; cnts[1] = 0; cnts[2] = 0; }
    __syncthreads();
    for (unsigned i = tid; i < n; i += T) {
        unsigned k = ck[i];
        if (((k - kbase) >> SH) >= Bf) {
            unsigned q = atomicAdd(&cnts[2], 1u);
            if (q < (unsigned)PFCAP) { pk[q] = k; pi[q] = ci[i]; }
        }
    }
    __syncthreads();
    unsigned pfCnt = cnts[2];
    bool useP = (pfCnt <= (unsigned)PFCAP);   // else: global-rescan fallback
    unsigned m = useP ? pfCnt : n;

    // ---- Round 1: bits [30:19] over source ----
    for (int i = tid; i < 4096; i += T) hist[i] = 0;
    __syncthreads();
    for (unsigned i = tid; i < m; i += T) {
        unsigned k = useP ? pk[i] : ck[i];
        atomicAdd(&hist[k >> 19], 1u);
    }
    __syncthreads();
    wave_select(hist, 4096, KTOP, resv, tid);
    __syncthreads();
    unsigned b1 = resv[0], r2 = resv[1];
    __syncthreads();

    // ---- Round 2: bits [18:7] within bin b1 ----
    for (int i = tid; i < 4096; i += T) hist[i] = 0;
    __syncthreads();
    for (unsigned i = tid; i < m; i += T) {
        unsigned k = useP ? pk[i] : ck[i];
        if ((k >> 19) == b1) atomicAdd(&hist[(k >> 7) & 0xFFFu], 1u);
    }
    __syncthreads();
    wave_select(hist, 4096, r2, resv, tid);
    __syncthreads();
    unsigned b2 = resv[0], r3 = resv[1];
    __syncthreads();

    // ---- Round 3: bits [6:0] ----
    for (int i = tid; i < 128; i += T) hist[i] = 0;
    __syncthreads();
    unsigned pref = (b1 << 12) | b2;
    for (unsigned i = tid; i < m; i += T) {
        unsigned k = useP ? pk[i] : ck[i];
        if ((k >> 7) == pref) atomicAdd(&hist[k & 127u], 1u);
    }
    __syncthreads();
    wave_select(hist, 128, r3, resv, tid);
    __syncthreads();
    unsigned b3 = resv[0], needEq = resv[1];
    unsigned K400 = (b1 << 19) | (b2 << 7) | b3;
    __syncthreads();

    // ---- compaction from source ----
    for (int i = tid; i < 512; i += T) { selk[i] = 0u; seli[i] = 0xFFFFFFFFu; }
    for (int i = tid; i < EQCAP; i += T) eqi[i] = 0xFFFFFFFFu;
    __syncthreads();
    for (unsigned i = tid; i < m; i += T) {
        unsigned k = useP ? pk[i] : ck[i];
        if (k > K400) {
            unsigned idx = useP ? pi[i] : ci[i];
            unsigned p = atomicAdd(&cnts[0], 1u);
            if (p < 512u) { selk[p] = k; seli[p] = idx; }
        } else if (k == K400) {
            unsigned idx = useP ? pi[i] : ci[i];
            unsigned q = atomicAdd(&cnts[1], 1u);
            if (q < (unsigned)EQCAP) eqi[q] = idx;
        }
    }
    __syncthreads();
    unsigned selCnt = uminu(cnts[0], (unsigned)KTOP);
    unsigned eqN   = uminu(cnts[1], (unsigned)EQCAP);

    // ---- tie list: only sort if we must pick a strict subset ----
    if (eqN > needEq) {
        int P2 = 1; while ((unsigned)P2 < eqN) P2 <<= 1;
        for (int k2 = 2; k2 <= P2; k2 <<= 1) {
            for (int j = k2 >> 1; j > 0; j >>= 1) {
                __syncthreads();
                for (int i = tid; i < P2; i += T) {
                    int ixj = i ^ j;
                    if (ixj > i && ixj < P2) {
                        unsigned va = eqi[i], vb = eqi[ixj];
                        bool up = ((i & k2) == 0);
                        if (up ? (va > vb) : (va < vb)) { eqi[i] = vb; eqi[ixj] = va; }
                    }
                }
            }
        }
        __syncthreads();
    }
    for (unsigned t2v = tid; t2v < needEq; t2v += T) {
        unsigned p = selCnt + t2v;
        if (p < KTOP) { selk[p] = K400; seli[p] = eqi[t2v]; }
    }
    __syncthreads();

    // ---- rank-scatter (replaces bitonic sort; 1 barrier) ----
    // Strict total order on (key desc, idx asc): real items (exactly KTOP of
    // them) have distinct idx -> unique ranks 0..KTOP-1. The 112 empty slots
    // (key=0, idx=~0) are identical and all land at rank KTOP (same-value
    // collision, slot never read: decode consumes ranks < KTOP only).
    if (tid < 512) {
        unsigned ki = selk[tid], ii = seli[tid];
        int r = 0;
        #pragma unroll 8
        for (int j = 0; j < 512; j++) {
            unsigned kj = selk[j], ij = seli[j];
            bool before = (kj > ki) || (kj == ki && ij < ii);
            r += before ? 1 : 0;
        }
        if (r < 512) { sk2[r] = ki; si2[r] = ii; }
    }
    __syncthreads();

    // ---- gather + on-the-fly box decode; write det arrays (coalesced) ----
    if (tid < KTOP) {
        unsigned idx = si2[tid];
        int o = b * KTOP + tid;
        if (idx == 0xFFFFFFFFu) {          // impossible on valid data; no OOB
            dX1[o] = -1.f; dY1[o] = -1.f; dX2[o] = -1.f; dY2[o] = -1.f;
            dSC[o] = __uint_as_float(sk2[tid]); dCID[o] = 0u;
        } else {
            const float* tip; const float* anc; int HW, W, candOff; float strideF;
            if (idx < 86640u)       { tip = t0; anc = anc0; HW = 361;  W = 19; strideF = 32.f; candOff = 0; }
            else if (idx < 433200u) { tip = t1; anc = anc1; HW = 1444; W = 38; strideF = 16.f; candOff = 86640; }
            else                    { tip = t2; anc = anc2; HW = 5776; W = 76; strideF = 8.f;  candOff = 433200; }
            unsigned local = idx - (unsigned)candOff;
            int cls = (int)(local % NUMC);
            int nn  = (int)(local / NUMC);
            int a = nn % NUMA, hwl = nn / NUMA;
            const float* base = tip + (size_t)(b * 255 + a * 85) * HW + hwl;
            float tx = base[0];
            float ty = base[(size_t)HW];
            float tw = base[(size_t)2 * HW];
            float th = base[(size_t)3 * HW];
            float fx = (float)(hwl % W), fy = (float)(hwl / W);
            float cx = (sigmoidf_(tx) + fx) * strideF;
            float cy = (sigmoidf_(ty) + fy) * strideF;
            float hw_ = expf(tw) * anc[2 * a]     * 0.5f;
            float hh_ = expf(th) * anc[2 * a + 1] * 0.5f;
            dX1[o] = cx - hw_; dY1[o] = cy - hh_;
            dX2[o] = cx + hw_; dY2[o] = cy + hh_;
            dSC[o] = __uint_as_float(sk2[tid]);
            dCID[o] = (unsigned)cls;
        }
    }
}

// ---------------- mask: parallel suppression-bitmask build (R7) ------------
// grid (11, 8) = 88 blocks: the O(K^2) IoU phase NEEDS breadth (R3/R6/R8
// all showed -40us when this ran on 8 blocks). Inner j-loop rotated by
// (t + 9w)&63 so the 7 w-groups (j0 = w*64, bank-0-aligned) read 7
// DIFFERENT banks each step; OR-accum is order-free.
__global__ __launch_bounds__(256) void mask_kernel(
        const float* __restrict__ dX1, const float* __restrict__ dY1,
        const float* __restrict__ dX2, const float* __restrict__ dY2,
        const unsigned* __restrict__ dCID, unsigned long long* __restrict__ maskG)
{
    __shared__ float lx1[KTOP], ly1[KTOP], lx2[KTOP], ly2[KTOP];
    __shared__ int lcid[KTOP];
    const int b = blockIdx.y;
    const int tid = threadIdx.x;
    for (int i = tid; i < KTOP; i += 256) {
        int o = b * KTOP + i;
        lx1[i] = dX1[o]; ly1[i] = dY1[o];
        lx2[i] = dX2[o]; ly2[i] = dY2[o];
        lcid[i] = (int)dCID[o];
    }
    __syncthreads();
    int p = blockIdx.x * 256 + tid;
    if (p < NMASK) {
        int i = p / 7, w = p - i * 7;
        float x1i = lx1[i], y1i = ly1[i], x2i = lx2[i], y2i = ly2[i];
        float ai = fmaxf(x2i - x1i, 0.f) * fmaxf(y2i - y1i, 0.f);
        int cidI = lcid[i];
        unsigned long long m = 0ull;
        int j0 = w * 64;
        int rot = (9 * w) & 63;
        for (int t = 0; t < 64; t++) {
            int j = j0 + ((t + rot) & 63);
            if (j >= KTOP || j <= i) continue;
            if (lcid[j] != cidI) continue;
            float iw = fminf(x2i, lx2[j]) - fmaxf(x1i, lx1[j]);
            float ih = fminf(y2i, ly2[j]) - fmaxf(y1i, ly1[j]);
            iw = fmaxf(iw, 0.f); ih = fmaxf(ih, 0.f);
            float inter = iw * ih;
            float aj = fmaxf(lx2[j] - lx1[j], 0.f) * fmaxf(ly2[j] - ly1[j], 0.f);
            float iou = inter / (ai + aj - inter + 1e-12f);
            if (iou > 0.45f) m |= (1ull << (j - j0));
        }
        maskG[(size_t)b * NMASK + p] = m;
    }
}

// ---------------- greedy + output: 8-deep prefetch ring (R7) ---------------
__global__ __launch_bounds__(512) void greedy_kernel(
        const float* __restrict__ dX1, const float* __restrict__ dY1,
        const float* __restrict__ dX2, const float* __restrict__ dY2,
        const float* __restrict__ dSC, const unsigned* __restrict__ dCID,
        const unsigned long long* __restrict__ maskG, float* __restrict__ out)
{
    __shared__ unsigned long long maskL[NMASK];
    __shared__ unsigned long long vkeep[7];
    __shared__ float oid[POST], osc[POST], obb[POST * 4];
    const int b = blockIdx.x;
    const int tid = threadIdx.x;

    for (int i = tid; i < NMASK; i += 512) maskL[i] = maskG[(size_t)b * NMASK + i];
    if (tid < POST) { oid[tid] = -1.f; osc[tid] = -1.f; }
    if (tid < POST * 4) obb[tid] = -1.f;
    __syncthreads();

    if (tid < 64) {
        const int lane = tid;
        unsigned long long keep = 0ull;
        if (lane < 7) keep = (lane == 6) ? 0xFFFFull : ~0ull;
        unsigned long long mb[8];
        #pragma unroll
        for (int k = 0; k < 8; k++)
            mb[k] = (lane < 7) ? maskL[k * 7 + lane] : 0ull;
        for (int ib = 0; ib < KTOP; ib += 8) {
            #pragma unroll
            for (int k = 0; k < 8; k++) {
                int i = ib + k;
                unsigned long long m = mb[k];
                int nf = ib + 8 + k;
                mb[k] = (lane < 7 && nf < KTOP) ? maskL[nf * 7 + lane] : 0ull;
                int w = i >> 6;  // wave-uniform
                unsigned klo = (unsigned)__builtin_amdgcn_readlane((int)(unsigned)(keep & 0xFFFFFFFFull), w);
                unsigned khi = (unsigned)__builtin_amdgcn_readlane((int)(unsigned)(keep >> 32), w);
                unsigned long long kw = ((unsigned long long)khi << 32) | klo;
                if ((kw >> (i & 63)) & 1ull) keep &= ~m;
            }
        }
        if (lane < 7) vkeep[lane] = keep;
    }
    __syncthreads();

    if (tid < KTOP) {
        int w = tid >> 6, bp = tid & 63;
        unsigned long long kw = vkeep[w];
        if ((kw >> bp) & 1ull) {
            int r = 0;
            for (int q = 0; q < w; q++) r += __popcll(vkeep[q]);
            r += __popcll(kw & ((1ull << bp) - 1ull));
            if (r < POST) {
                int o = b * KTOP + tid;
                oid[r] = (float)(int)dCID[o];
                osc[r] = dSC[o];
                obb[r * 4 + 0] = dX1[o];
                obb[r * 4 + 1] = dY1[o];
                obb[r * 4 + 2] = dX2[o];
                obb[r * 4 + 3] = dY2[o];
            }
        }
    }
    __syncthreads();
    if (tid < POST) {
        out[b * POST + tid]       = oid[tid];
        out[800 + b * POST + tid] = osc[tid];
    }
    if (tid < POST * 4) out[1600 + b * POST * 4 + tid] = obb[tid];
}

// ---------------------------------------------------------------------------
extern "C" void kernel_launch(void* const* d_in, const int* in_sizes, int n_in,
                              void* d_out, int out_size, void* d_ws, size_t ws_size,
                              hipStream_t stream)
{
    const float* tip0 = (const float*)d_in[0];
    const float* tip1 = (const float*)d_in[1];
    const float* tip2 = (const float*)d_in[2];
    const float* anc0 = (const float*)d_in[3];
    const float* anc1 = (const float*)d_in[4];
    const float* anc2 = (const float*)d_in[5];
    float* out = (float*)d_out;

    // ws layout (u32 unless noted): histN(8*NBIN) | ccnt(8) | ckey(8*CAP) |
    // cidx(8*CAP) | det 6x3200 f32 | maskG 8*2800 u64
    unsigned* histN = (unsigned*)d_ws;
    unsigned* ccnt  = histN + 8 * NBIN;
    unsigned* ckey  = ccnt + 8;
    unsigned* cidx  = ckey + (size_t)8 * CAP;
    float*    dX1   = (float*)(cidx + (size_t)8 * CAP);
    float*    dY1   = dX1 + 8 * KTOP;
    float*    dX2   = dY1 + 8 * KTOP;
    float*    dY2   = dX2 + 8 * KTOP;
    float*    dSC   = dY2 + 8 * KTOP;
    unsigned* dCID  = (unsigned*)(dSC + 8 * KTOP);
    unsigned long long* maskG = (unsigned long long*)(dCID + 8 * KTOP);

    // zero histN + ccnt in one stream-ordered (graph-capturable) memset
    hipMemsetAsync(histN, 0, (8 * NBIN + 8) * sizeof(unsigned), stream);

    dim3 g(10, 80 / CPB, 24);
    score_main<<<g, 256, 0, stream>>>(tip0, tip1, tip2, histN, ccnt, ckey, cidx);
    topk_sel<<<8, 1024, 0, stream>>>(tip0, tip1, tip2, anc0, anc1, anc2,
                                     histN, ccnt, ckey, cidx,
                                     dX1, dY1, dX2, dY2, dSC, dCID);
    mask_kernel<<<dim3((NMASK + 255) / 256, 8), 256, 0, stream>>>(
        dX1, dY1, dX2, dY2, dCID, maskG);
    greedy_kernel<<<8, 512, 0, stream>>>(dX1, dY1, dX2, dY2, dSC, dCID, maskG, out);
}

// Round 11
// 191.710 us; speedup vs baseline: 1.0221x; 1.0221x over previous
//
#include <hip/hip_runtime.h>
#include <stdint.h>

#define NUMA 3
#define NUMC 80
#define CAP  49152
#define KTOP 400
#define POST 100
#define EQCAP 1024
#define PFCAP 2048
#define KEY0 0x3EE66666u   // __float_as_uint(0.45f): static compact threshold
#define KEYTOP 0x3F800000u // __float_as_uint(1.0f): max possible score key
#define LBUF 1024          // per-block LDS candidate buffer
#define NMASK (KTOP * 7)   // 2800 mask words per image
#define CPB 20             // classes per score_main block
#define NBIN 2048          // coarse hist bins; (key-KEY0)>>13 spans 0..1228

typedef float f32x4 __attribute__((ext_vector_type(4)));

__device__ __forceinline__ float sigmoidf_(float x) { return 1.0f / (1.0f + expf(-x)); }
__device__ __forceinline__ unsigned uminu(unsigned a, unsigned b) { return a < b ? a : b; }

// Conservative raw-logit threshold: x > thr(cf) is NECESSARY for
// sigmoid(x)*cf >= 0.45f (margins 0.449 + 0.01 dwarf float error; the exact
// test still decides membership, so the candidate set is bit-identical).
// cf < 0.45f admits nothing: sc = round(sig*cf) <= cf < 0.45f.
__device__ __forceinline__ float thr_for(float cf) {
    if (!(cf >= 0.45f)) return 3.0e38f;
    float q = 0.449f / cf;             // < 1 guaranteed (cf >= 0.45)
    float r = q / (1.0f - q);
    return logf(r) - 0.01f;
}

// ---------------- main pass: decode + LDS compact + coarse hist ------------
// Coarse histogram (R0 structure, measured-free there: only ~0.75% of evals
// hit the LDS atomic) lets topk_sel's warm path skip its full key re-scan.
// Binning (key-KEY0)>>13 == topk_sel's SH=13/kbase=KEY0. Overflow (>LBUF)
// poisons ccnt -> cold path ignores histN -> exact.
__global__ __launch_bounds__(256) void score_main(
        const float* __restrict__ t0, const float* __restrict__ t1,
        const float* __restrict__ t2,
        unsigned* __restrict__ histN, unsigned* __restrict__ ccnt,
        unsigned* __restrict__ ckey, unsigned* __restrict__ cidx)
{
    __shared__ unsigned lkey[LBUF], lidx[LBUF];
    __shared__ unsigned lh[NBIN];
    __shared__ unsigned lcnt, lbase;
    const int tid = threadIdx.x;
    if (tid == 0) lcnt = 0;
    for (int i = tid; i < NBIN; i += 256) lh[i] = 0;
    __syncthreads();

    const int ba = blockIdx.z;
    const int b = ba / 3, a = ba - 3 * b;
    const int c0 = blockIdx.y * CPB;
    const int cx = blockIdx.x;

    #define LEMIT(SC, IDX) do { \
        unsigned key_ = __float_as_uint(SC); \
        if (key_ >= KEY0) { \
            atomicAdd(&lh[(key_ - KEY0) >> 13], 1u); \
            unsigned pos_ = atomicAdd(&lcnt, 1u); \
            if (pos_ < LBUF) { lkey[pos_] = key_; lidx[pos_] = (IDX); } \
        } \
    } while (0)

    if (cx < 2) {
        const int hw = cx * 256 + tid;
        if (hw < 361) {
            const float* base = t0 + (size_t)(b * 255 + a * 85) * 361;
            float cr = base[4 * 361 + hw];
            const float* p0 = base + (size_t)(5 + c0) * 361 + hw;
            float xv[CPB];
            #pragma unroll
            for (int u = 0; u < CPB; u++) xv[u] = p0[u * 361];
            float cf = sigmoidf_(cr);
            float xt = thr_for(cf);
            unsigned ib = (unsigned)((hw * NUMA + a) * NUMC + c0);
            #pragma unroll
            for (int u = 0; u < CPB; u++)
                if (xv[u] > xt) LEMIT(sigmoidf_(xv[u]) * cf, ib + (unsigned)u);
        }
    } else {
        const float* tip; int vHW, v, candOff;
        if (cx < 4) { tip = t1; vHW = 361;  v = (cx - 2) * 256 + tid; candOff = 86640; }
        else        { tip = t2; vHW = 1444; v = (cx - 4) * 256 + tid; candOff = 433200; }
        if (v < vHW) {
            const f32x4* bp = (const f32x4*)(tip + (size_t)(b * 255 + a * 85) * (size_t)(vHW * 4));
            f32x4 cv = bp[(size_t)4 * vHW + v];
            const f32x4* p0 = bp + (size_t)(5 + c0) * vHW + v;
            f32x4 sv[CPB];
            #pragma unroll
            for (int u = 0; u < CPB; u++) sv[u] = p0[(size_t)u * vHW];
            float cf0 = sigmoidf_(cv[0]), cf1 = sigmoidf_(cv[1]);
            float cf2 = sigmoidf_(cv[2]), cf3 = sigmoidf_(cv[3]);
            float xt0 = thr_for(cf0), xt1 = thr_for(cf1);
            float xt2 = thr_for(cf2), xt3 = thr_for(cf3);
            unsigned ib0 = (unsigned)(candOff + (v * 4 * NUMA + a) * NUMC + c0);
            #pragma unroll
            for (int u = 0; u < CPB; u++) {
                unsigned ib = ib0 + (unsigned)u;
                if (sv[u][0] > xt0) LEMIT(sigmoidf_(sv[u][0]) * cf0, ib);
                if (sv[u][1] > xt1) LEMIT(sigmoidf_(sv[u][1]) * cf1, ib + 240);
                if (sv[u][2] > xt2) LEMIT(sigmoidf_(sv[u][2]) * cf2, ib + 480);
                if (sv[u][3] > xt3) LEMIT(sigmoidf_(sv[u][3]) * cf3, ib + 720);
            }
        }
    }
    #undef LEMIT

    __syncthreads();
    if (tid == 0) {
        unsigned c = lcnt;
        if (c > LBUF) {
            atomicOr(&ccnt[b], 0x80000000u);
            lbase = 0xFFFFFFFFu;
        } else {
            lbase = atomicAdd(&ccnt[b], c);
        }
    }
    __syncthreads();
    unsigned c = uminu(lcnt, (unsigned)LBUF);
    unsigned basep = lbase;
    if (basep != 0xFFFFFFFFu) {
        for (unsigned i = tid; i < c; i += 256) {
            unsigned p = basep + i;
            if (p < CAP) {
                ckey[(size_t)b * CAP + p] = lkey[i];
                cidx[(size_t)b * CAP + p] = lidx[i];
            }
        }
    }
    unsigned* gh = histN + b * NBIN;
    for (int i = tid; i < NBIN; i += 256) {
        unsigned v2 = lh[i];
        if (v2) atomicAdd(&gh[i], v2);
    }
}

// ---------------- wave-parallel rank select over an LDS histogram ----------
__device__ __forceinline__ void wave_select(const unsigned* h, int nbins, unsigned rank,
                                            unsigned* resv, int tid)
{
    if (tid >= 64) return;
    const int lane = tid;
    const int cs = nbins >> 6;
    unsigned v = 0;
    for (int k = 0; k < cs; k++) {
        int off = (k + lane) & (cs - 1);
        v += h[lane * cs + off];
    }
    unsigned S = v;
    #pragma unroll
    for (int o = 1; o < 64; o <<= 1) {
        unsigned t = (unsigned)__shfl_down((int)S, o);
        if (lane + o < 64) S += t;
    }
    unsigned long long bm = __ballot(S >= rank);
    if (bm == 0ull) bm = 1ull;
    int C = 63 - __builtin_clzll(bm);
    unsigned SC = (unsigned)__builtin_amdgcn_readlane((int)S, C);
    unsigned vC = (unsigned)__builtin_amdgcn_readlane((int)v, C);
    unsigned rem = rank - (SC - vC);
    unsigned w = (lane < cs) ? h[C * cs + lane] : 0u;
    unsigned T = w;
    #pragma unroll
    for (int o = 1; o < 64; o <<= 1) {
        unsigned t = (unsigned)__shfl_down((int)T, o);
        if (lane + o < 64) T += t;
    }
    unsigned long long bm2 = __ballot((T >= rem) && (lane < cs));
    if (bm2 == 0ull) bm2 = 1ull;
    int B = 63 - __builtin_clzll(bm2);
    unsigned TB = (unsigned)__builtin_amdgcn_readlane((int)T, B);
    unsigned wB = (unsigned)__builtin_amdgcn_readlane((int)w, B);
    if (lane == 0) {
        resv[0] = (unsigned)(C * cs + B);
        resv[1] = rem - (TB - wB);
    }
}

// ---------------- topk_sel: (cold fb) + select + bitonic + decode ----------
// R11: R10's histN warm path kept (Phase A full-key scan elided); R10's
// rank-scatter REVERTED to the R9 bitonic sort (rank-scatter did 512
// LDS reads/thread = ~10x the bitonic's total LDS traffic -> +7us, R10).
__global__ __launch_bounds__(1024) void topk_sel(
        const float* __restrict__ t0, const float* __restrict__ t1,
        const float* __restrict__ t2,
        const float* __restrict__ anc0, const float* __restrict__ anc1,
        const float* __restrict__ anc2,
        const unsigned* __restrict__ histN, const unsigned* __restrict__ ccnt,
        unsigned* __restrict__ ckey, unsigned* __restrict__ cidx,
        float* __restrict__ dX1, float* __restrict__ dY1,
        float* __restrict__ dX2, float* __restrict__ dY2,
        float* __restrict__ dSC, unsigned* __restrict__ dCID)
{
    const int b = blockIdx.x;
    const int tid = threadIdx.x;
    const int T = 1024;

    __shared__ unsigned hist[4096];
    __shared__ unsigned resv[2];
    __shared__ unsigned selk[512], seli[512];
    __shared__ unsigned eqi[EQCAP];
    __shared__ unsigned pk[PFCAP], pi[PFCAP];
    __shared__ unsigned cnts[3];   // 0: sel count, 1: eq count, 2: prefilter count
    __shared__ unsigned fcnt;

    unsigned* ck = ckey + (size_t)b * CAP;
    unsigned* ci = cidx + (size_t)b * CAP;
    unsigned nraw = ccnt[b];
    unsigned kbase = KEY0;
    unsigned SH = 13;              // matches score_main's (key-KEY0)>>13

    bool cold = !(nraw >= KTOP && nraw <= CAP);
    if (cold) {
        // ---- COLD fallback: static 0.45 cut invalid for this image ----
        const int NPOS = 3 * (361 + 1444 + 5776);   // 22743 (anchor,pos) pairs
        for (int i = tid; i < 2048; i += T) hist[i] = 0;
        if (tid == 0) fcnt = 0;
        __syncthreads();
        // pass 1: histogram all 1.8M scores by key >> 19
        for (int p = tid; p < NPOS; p += T) {
            const float* tip; int HW, pp;
            if (p < 1083)      { tip = t0; HW = 361;  pp = p; }
            else if (p < 5415) { tip = t1; HW = 1444; pp = p - 1083; }
            else               { tip = t2; HW = 5776; pp = p - 5415; }
            int a = pp / HW, hwl = pp - a * HW;
            const float* base = tip + (size_t)(b * 255 + a * 85) * HW;
            float cf = sigmoidf_(base[4 * HW + hwl]);
            for (int u = 0; u < NUMC; u++) {
                float sc = sigmoidf_(base[(size_t)(5 + u) * HW + hwl]) * cf;
                atomicAdd(&hist[__float_as_uint(sc) >> 19], 1u);
            }
        }
        __syncthreads();
        wave_select(hist, 2048, KTOP, resv, tid);
        __syncthreads();
        unsigned cutkey = resv[0] << 19;
        __syncthreads();
        // pass 2: recompact with the exact bin cut (global ckey/cidx)
        for (int p = tid; p < NPOS; p += T) {
            const float* tip; int HW, pp, candOff;
            if (p < 1083)      { tip = t0; HW = 361;  pp = p;        candOff = 0; }
            else if (p < 5415) { tip = t1; HW = 1444; pp = p - 1083; candOff = 86640; }
            else               { tip = t2; HW = 5776; pp = p - 5415; candOff = 433200; }
            int a = pp / HW, hwl = pp - a * HW;
            const float* base = tip + (size_t)(b * 255 + a * 85) * HW;
            float cf = sigmoidf_(base[4 * HW + hwl]);
            unsigned ib0 = (unsigned)(candOff + (hwl * NUMA + a) * NUMC);
            for (int u = 0; u < NUMC; u++) {
                float sc = sigmoidf_(base[(size_t)(5 + u) * HW + hwl]) * cf;
                unsigned key = __float_as_uint(sc);
                if (key >= cutkey) {
                    unsigned pos = atomicAdd(&fcnt, 1u);
                    if (pos < CAP) { ck[pos] = key; ci[pos] = ib0 + (unsigned)u; }
                }
            }
        }
        __syncthreads();
        nraw = fcnt;
        kbase = cutkey;
        unsigned span = (KEYTOP - kbase) + 1u;
        SH = 0;
        while ((span >> SH) > 2047u) SH++;
    }
    unsigned n = uminu(nraw, (unsigned)CAP);

    // ---- Phase A: coarse hist. Warm: load prebuilt histN. Cold: build. ----
    if (cold) {
        for (int i = tid; i < 2048; i += T) hist[i] = 0;
        __syncthreads();
        unsigned n4 = n >> 2;
        const uint4* ck4 = (const uint4*)ck;
        for (unsigned i = tid; i < n4; i += T) {
            uint4 k = ck4[i];
            atomicAdd(&hist[(k.x - kbase) >> SH], 1u);
            atomicAdd(&hist[(k.y - kbase) >> SH], 1u);
            atomicAdd(&hist[(k.z - kbase) >> SH], 1u);
            atomicAdd(&hist[(k.w - kbase) >> SH], 1u);
        }
        for (unsigned i = (n4 << 2) + tid; i < n; i += T)
            atomicAdd(&hist[(ck[i] - kbase) >> SH], 1u);
    } else {
        for (int i = tid; i < 2048; i += T) hist[i] = histN[b * NBIN + i];
    }
    __syncthreads();
    wave_select(hist, 2048, KTOP, resv, tid);
    __syncthreads();
    unsigned Bf = resv[0];            // rank-400 floor bin
    __syncthreads();

    // ---- Phase B: compact bins >= Bf into LDS (pk/pi) ----
    if (tid == 0) { cnts[0] = 0; cnts[1] = 0; cnts[2] = 0; }
    __syncthreads();
    for (unsigned i = tid; i < n; i += T) {
        unsigned k = ck[i];
        if (((k - kbase) >> SH) >= Bf) {
            unsigned q = atomicAdd(&cnts[2], 1u);
            if (q < (unsigned)PFCAP) { pk[q] = k; pi[q] = ci[i]; }
        }
    }
    __syncthreads();
    unsigned pfCnt = cnts[2];
    bool useP = (pfCnt <= (unsigned)PFCAP);   // else: global-rescan fallback
    unsigned m = useP ? pfCnt : n;

    // ---- Round 1: bits [30:19] over source ----
    for (int i = tid; i < 4096; i += T) hist[i] = 0;
    __syncthreads();
    for (unsigned i = tid; i < m; i += T) {
        unsigned k = useP ? pk[i] : ck[i];
        atomicAdd(&hist[k >> 19], 1u);
    }
    __syncthreads();
    wave_select(hist, 4096, KTOP, resv, tid);
    __syncthreads();
    unsigned b1 = resv[0], r2 = resv[1];
    __syncthreads();

    // ---- Round 2: bits [18:7] within bin b1 ----
    for (int i = tid; i < 4096; i += T) hist[i] = 0;
    __syncthreads();
    for (unsigned i = tid; i < m; i += T) {
        unsigned k = useP ? pk[i] : ck[i];
        if ((k >> 19) == b1) atomicAdd(&hist[(k >> 7) & 0xFFFu], 1u);
    }
    __syncthreads();
    wave_select(hist, 4096, r2, resv, tid);
    __syncthreads();
    unsigned b2 = resv[0], r3 = resv[1];
    __syncthreads();

    // ---- Round 3: bits [6:0] ----
    for (int i = tid; i < 128; i += T) hist[i] = 0;
    __syncthreads();
    unsigned pref = (b1 << 12) | b2;
    for (unsigned i = tid; i < m; i += T) {
        unsigned k = useP ? pk[i] : ck[i];
        if ((k >> 7) == pref) atomicAdd(&hist[k & 127u], 1u);
    }
    __syncthreads();
    wave_select(hist, 128, r3, resv, tid);
    __syncthreads();
    unsigned b3 = resv[0], needEq = resv[1];
    unsigned K400 = (b1 << 19) | (b2 << 7) | b3;
    __syncthreads();

    // ---- compaction from source ----
    for (int i = tid; i < 512; i += T) { selk[i] = 0u; seli[i] = 0xFFFFFFFFu; }
    for (int i = tid; i < EQCAP; i += T) eqi[i] = 0xFFFFFFFFu;
    __syncthreads();
    for (unsigned i = tid; i < m; i += T) {
        unsigned k = useP ? pk[i] : ck[i];
        if (k > K400) {
            unsigned idx = useP ? pi[i] : ci[i];
            unsigned p = atomicAdd(&cnts[0], 1u);
            if (p < 512u) { selk[p] = k; seli[p] = idx; }
        } else if (k == K400) {
            unsigned idx = useP ? pi[i] : ci[i];
            unsigned q = atomicAdd(&cnts[1], 1u);
            if (q < (unsigned)EQCAP) eqi[q] = idx;
        }
    }
    __syncthreads();
    unsigned selCnt = uminu(cnts[0], (unsigned)KTOP);
    unsigned eqN   = uminu(cnts[1], (unsigned)EQCAP);

    // ---- tie list: only sort if we must pick a strict subset ----
    if (eqN > needEq) {
        int P2 = 1; while ((unsigned)P2 < eqN) P2 <<= 1;
        for (int k2 = 2; k2 <= P2; k2 <<= 1) {
            for (int j = k2 >> 1; j > 0; j >>= 1) {
                __syncthreads();
                for (int i = tid; i < P2; i += T) {
                    int ixj = i ^ j;
                    if (ixj > i && ixj < P2) {
                        unsigned va = eqi[i], vb = eqi[ixj];
                        bool up = ((i & k2) == 0);
                        if (up ? (va > vb) : (va < vb)) { eqi[i] = vb; eqi[ixj] = va; }
                    }
                }
            }
        }
        __syncthreads();
    }
    for (unsigned t2v = tid; t2v < needEq; t2v += T) {
        unsigned p = selCnt + t2v;
        if (p < KTOP) { selk[p] = K400; seli[p] = eqi[t2v]; }
    }
    __syncthreads();

    // ---- bitonic sort 512 by (key desc, idx asc); j<64 passes in-wave ----
    for (int k2 = 2; k2 <= 512; k2 <<= 1) {
        int j = k2 >> 1;
        for (; j >= 64; j >>= 1) {
            __syncthreads();
            if (tid < 512) {
                int i = tid, ixj = i ^ j;
                if (ixj > i) {
                    unsigned ka = selk[i], kb = selk[ixj], ia = seli[i], ib = seli[ixj];
                    bool before = (ka > kb) || (ka == kb && ia < ib);
                    bool up = ((i & k2) == 0);
                    if (up ? !before : before) {
                        selk[i] = kb; selk[ixj] = ka; seli[i] = ib; seli[ixj] = ia;
                    }
                }
            }
        }
        __syncthreads();
        if (tid < 512) {
            for (; j > 0; j >>= 1) {
                int i = tid, ixj = i ^ j;
                if (ixj > i) {
                    unsigned ka = selk[i], kb = selk[ixj], ia = seli[i], ib = seli[ixj];
                    bool before = (ka > kb) || (ka == kb && ia < ib);
                    bool up = ((i & k2) == 0);
                    if (up ? !before : before) {
                        selk[i] = kb; selk[ixj] = ka; seli[i] = ib; seli[ixj] = ia;
                    }
                }
            }
        }
    }
    __syncthreads();

    // ---- gather + on-the-fly box decode; write det arrays (coalesced) ----
    if (tid < KTOP) {
        unsigned idx = seli[tid];
        int o = b * KTOP + tid;
        if (idx == 0xFFFFFFFFu) {          // impossible on valid data; no OOB
            dX1[o] = -1.f; dY1[o] = -1.f; dX2[o] = -1.f; dY2[o] = -1.f;
            dSC[o] = __uint_as_float(selk[tid]); dCID[o] = 0u;
        } else {
            const float* tip; const float* anc; int HW, W, candOff; float strideF;
            if (idx < 86640u)       { tip = t0; anc = anc0; HW = 361;  W = 19; strideF = 32.f; candOff = 0; }
            else if (idx < 433200u) { tip = t1; anc = anc1; HW = 1444; W = 38; strideF = 16.f; candOff = 86640; }
            else                    { tip = t2; anc = anc2; HW = 5776; W = 76; strideF = 8.f;  candOff = 433200; }
            unsigned local = idx - (unsigned)candOff;
            int cls = (int)(local % NUMC);
            int nn  = (int)(local / NUMC);
            int a = nn % NUMA, hwl = nn / NUMA;
            const float* base = tip + (size_t)(b * 255 + a * 85) * HW + hwl;
            float tx = base[0];
            float ty = base[(size_t)HW];
            float tw = base[(size_t)2 * HW];
            float th = base[(size_t)3 * HW];
            float fx = (float)(hwl % W), fy = (float)(hwl / W);
            float cx = (sigmoidf_(tx) + fx) * strideF;
            float cy = (sigmoidf_(ty) + fy) * strideF;
            float hw_ = expf(tw) * anc[2 * a]     * 0.5f;
            float hh_ = expf(th) * anc[2 * a + 1] * 0.5f;
            dX1[o] = cx - hw_; dY1[o] = cy - hh_;
            dX2[o] = cx + hw_; dY2[o] = cy + hh_;
            dSC[o] = __uint_as_float(selk[tid]);
            dCID[o] = (unsigned)cls;
        }
    }
}

// ---------------- mask: parallel suppression-bitmask build (R7) ------------
// grid (11, 8) = 88 blocks: the O(K^2) IoU phase NEEDS breadth (R3/R6/R8
// all showed -40us when this ran on 8 blocks). Inner j-loop rotated by
// (t + 9w)&63 so the 7 w-groups (j0 = w*64, bank-0-aligned) read 7
// DIFFERENT banks each step; OR-accum is order-free.
__global__ __launch_bounds__(256) void mask_kernel(
        const float* __restrict__ dX1, const float* __restrict__ dY1,
        const float* __restrict__ dX2, const float* __restrict__ dY2,
        const unsigned* __restrict__ dCID, unsigned long long* __restrict__ maskG)
{
    __shared__ float lx1[KTOP], ly1[KTOP], lx2[KTOP], ly2[KTOP];
    __shared__ int lcid[KTOP];
    const int b = blockIdx.y;
    const int tid = threadIdx.x;
    for (int i = tid; i < KTOP; i += 256) {
        int o = b * KTOP + i;
        lx1[i] = dX1[o]; ly1[i] = dY1[o];
        lx2[i] = dX2[o]; ly2[i] = dY2[o];
        lcid[i] = (int)dCID[o];
    }
    __syncthreads();
    int p = blockIdx.x * 256 + tid;
    if (p < NMASK) {
        int i = p / 7, w = p - i * 7;
        float x1i = lx1[i], y1i = ly1[i], x2i = lx2[i], y2i = ly2[i];
        float ai = fmaxf(x2i - x1i, 0.f) * fmaxf(y2i - y1i, 0.f);
        int cidI = lcid[i];
        unsigned long long m = 0ull;
        int j0 = w * 64;
        int rot = (9 * w) & 63;
        for (int t = 0; t < 64; t++) {
            int j = j0 + ((t + rot) & 63);
            if (j >= KTOP || j <= i) continue;
            if (lcid[j] != cidI) continue;
            float iw = fminf(x2i, lx2[j]) - fmaxf(x1i, lx1[j]);
            float ih = fminf(y2i, ly2[j]) - fmaxf(y1i, ly1[j]);
            iw = fmaxf(iw, 0.f); ih = fmaxf(ih, 0.f);
            float inter = iw * ih;
            float aj = fmaxf(lx2[j] - lx1[j], 0.f) * fmaxf(ly2[j] - ly1[j], 0.f);
            float iou = inter / (ai + aj - inter + 1e-12f);
            if (iou > 0.45f) m |= (1ull << (j - j0));
        }
        maskG[(size_t)b * NMASK + p] = m;
    }
}

// ---------------- greedy + output: 8-deep prefetch ring (R7) ---------------
__global__ __launch_bounds__(512) void greedy_kernel(
        const float* __restrict__ dX1, const float* __restrict__ dY1,
        const float* __restrict__ dX2, const float* __restrict__ dY2,
        const float* __restrict__ dSC, const unsigned* __restrict__ dCID,
        const unsigned long long* __restrict__ maskG, float* __restrict__ out)
{
    __shared__ unsigned long long maskL[NMASK];
    __shared__ unsigned long long vkeep[7];
    __shared__ float oid[POST], osc[POST], obb[POST * 4];
    const int b = blockIdx.x;
    const int tid = threadIdx.x;

    for (int i = tid; i < NMASK; i += 512) maskL[i] = maskG[(size_t)b * NMASK + i];
    if (tid < POST) { oid[tid] = -1.f; osc[tid] = -1.f; }
    if (tid < POST * 4) obb[tid] = -1.f;
    __syncthreads();

    if (tid < 64) {
        const int lane = tid;
        unsigned long long keep = 0ull;
        if (lane < 7) keep = (lane == 6) ? 0xFFFFull : ~0ull;
        unsigned long long mb[8];
        #pragma unroll
        for (int k = 0; k < 8; k++)
            mb[k] = (lane < 7) ? maskL[k * 7 + lane] : 0ull;
        for (int ib = 0; ib < KTOP; ib += 8) {
            #pragma unroll
            for (int k = 0; k < 8; k++) {
                int i = ib + k;
                unsigned long long m = mb[k];
                int nf = ib + 8 + k;
                mb[k] = (lane < 7 && nf < KTOP) ? maskL[nf * 7 + lane] : 0ull;
                int w = i >> 6;  // wave-uniform
                unsigned klo = (unsigned)__builtin_amdgcn_readlane((int)(unsigned)(keep & 0xFFFFFFFFull), w);
                unsigned khi = (unsigned)__builtin_amdgcn_readlane((int)(unsigned)(keep >> 32), w);
                unsigned long long kw = ((unsigned long long)khi << 32) | klo;
                if ((kw >> (i & 63)) & 1ull) keep &= ~m;
            }
        }
        if (lane < 7) vkeep[lane] = keep;
    }
    __syncthreads();

    if (tid < KTOP) {
        int w = tid >> 6, bp = tid & 63;
        unsigned long long kw = vkeep[w];
        if ((kw >> bp) & 1ull) {
            int r = 0;
            for (int q = 0; q < w; q++) r += __popcll(vkeep[q]);
            r += __popcll(kw & ((1ull << bp) - 1ull));
            if (r < POST) {
                int o = b * KTOP + tid;
                oid[r] = (float)(int)dCID[o];
                osc[r] = dSC[o];
                obb[r * 4 + 0] = dX1[o];
                obb[r * 4 + 1] = dY1[o];
                obb[r * 4 + 2] = dX2[o];
                obb[r * 4 + 3] = dY2[o];
            }
        }
    }
    __syncthreads();
    if (tid < POST) {
        out[b * POST + tid]       = oid[tid];
        out[800 + b * POST + tid] = osc[tid];
    }
    if (tid < POST * 4) out[1600 + b * POST * 4 + tid] = obb[tid];
}

// ---------------------------------------------------------------------------
extern "C" void kernel_launch(void* const* d_in, const int* in_sizes, int n_in,
                              void* d_out, int out_size, void* d_ws, size_t ws_size,
                              hipStream_t stream)
{
    const float* tip0 = (const float*)d_in[0];
    const float* tip1 = (const float*)d_in[1];
    const float* tip2 = (const float*)d_in[2];
    const float* anc0 = (const float*)d_in[3];
    const float* anc1 = (const float*)d_in[4];
    const float* anc2 = (const float*)d_in[5];
    float* out = (float*)d_out;

    // ws layout (u32 unless noted): histN(8*NBIN) | ccnt(8) | ckey(8*CAP) |
    // cidx(8*CAP) | det 6x3200 f32 | maskG 8*2800 u64
    unsigned* histN = (unsigned*)d_ws;
    unsigned* ccnt  = histN + 8 * NBIN;
    unsigned* ckey  = ccnt + 8;
    unsigned* cidx  = ckey + (size_t)8 * CAP;
    float*    dX1   = (float*)(cidx + (size_t)8 * CAP);
    float*    dY1   = dX1 + 8 * KTOP;
    float*    dX2   = dY1 + 8 * KTOP;
    float*    dY2   = dX2 + 8 * KTOP;
    float*    dSC   = dY2 + 8 * KTOP;
    unsigned* dCID  = (unsigned*)(dSC + 8 * KTOP);
    unsigned long long* maskG = (unsigned long long*)(dCID + 8 * KTOP);

    // zero histN + ccnt in one stream-ordered (graph-capturable) memset
    hipMemsetAsync(histN, 0, (8 * NBIN + 8) * sizeof(unsigned), stream);

    dim3 g(10, 80 / CPB, 24);
    score_main<<<g, 256, 0, stream>>>(tip0, tip1, tip2, histN, ccnt, ckey, cidx);
    topk_sel<<<8, 1024, 0, stream>>>(tip0, tip1, tip2, anc0, anc1, anc2,
                                     histN, ccnt, ckey, cidx,
                                     dX1, dY1, dX2, dY2, dSC, dCID);
    mask_kernel<<<dim3((NMASK + 255) / 256, 8), 256, 0, stream>>>(
        dX1, dY1, dX2, dY2, dCID, maskG);
    greedy_kernel<<<8, 512, 0, stream>>>(dX1, dY1, dX2, dY2, dSC, dCID, maskG, out);
}

// Round 12
// 185.874 us; speedup vs baseline: 1.0542x; 1.0314x over previous
//
#include <hip/hip_runtime.h>
#include <stdint.h>

#define NUMA 3
#define NUMC 80
#define CAP  49152
#define KTOP 400
#define POST 100
#define EQCAP 1024
#define PFCAP 2048
#define KEY0 0x3EE66666u   // __float_as_uint(0.45f): static compact threshold
#define KEYTOP 0x3F800000u // __float_as_uint(1.0f): max possible score key
#define LBUF 1024          // per-block LDS candidate buffer
#define NMASK (KTOP * 7)   // 2800 mask words per image
#define CPB 20             // classes per score_main block
#define NBIN 2048          // coarse hist bins; (key-KEY0)>>13 spans 0..1228

typedef float f32x4 __attribute__((ext_vector_type(4)));

__device__ __forceinline__ float sigmoidf_(float x) { return 1.0f / (1.0f + expf(-x)); }
__device__ __forceinline__ unsigned uminu(unsigned a, unsigned b) { return a < b ? a : b; }

// Conservative raw-logit threshold: x > thr(cf) is NECESSARY for
// sigmoid(x)*cf >= 0.45f (margins 0.449 + 0.01 dwarf float error; the exact
// test still decides membership, so the candidate set is bit-identical).
// cf < 0.45f admits nothing: sc = round(sig*cf) <= cf < 0.45f.
__device__ __forceinline__ float thr_for(float cf) {
    if (!(cf >= 0.45f)) return 3.0e38f;
    float q = 0.449f / cf;             // < 1 guaranteed (cf >= 0.45)
    float r = q / (1.0f - q);
    return logf(r) - 0.01f;
}

// ---------------- main pass: decode + LDS compact + coarse hist ------------
// Coarse histogram (R0 structure, measured-free there: only ~0.75% of evals
// hit the LDS atomic) lets topk_sel's warm path skip its full key re-scan.
// Binning (key-KEY0)>>13 == topk_sel's SH=13/kbase=KEY0. Overflow (>LBUF)
// poisons ccnt -> cold path ignores histN -> exact.
__global__ __launch_bounds__(256) void score_main(
        const float* __restrict__ t0, const float* __restrict__ t1,
        const float* __restrict__ t2,
        unsigned* __restrict__ histN, unsigned* __restrict__ ccnt,
        unsigned* __restrict__ ckey, unsigned* __restrict__ cidx)
{
    __shared__ unsigned lkey[LBUF], lidx[LBUF];
    __shared__ unsigned lh[NBIN];
    __shared__ unsigned lcnt, lbase;
    const int tid = threadIdx.x;
    if (tid == 0) lcnt = 0;
    for (int i = tid; i < NBIN; i += 256) lh[i] = 0;
    __syncthreads();

    const int ba = blockIdx.z;
    const int b = ba / 3, a = ba - 3 * b;
    const int c0 = blockIdx.y * CPB;
    const int cx = blockIdx.x;

    #define LEMIT(SC, IDX) do { \
        unsigned key_ = __float_as_uint(SC); \
        if (key_ >= KEY0) { \
            atomicAdd(&lh[(key_ - KEY0) >> 13], 1u); \
            unsigned pos_ = atomicAdd(&lcnt, 1u); \
            if (pos_ < LBUF) { lkey[pos_] = key_; lidx[pos_] = (IDX); } \
        } \
    } while (0)

    if (cx < 2) {
        const int hw = cx * 256 + tid;
        if (hw < 361) {
            const float* base = t0 + (size_t)(b * 255 + a * 85) * 361;
            float cr = base[4 * 361 + hw];
            const float* p0 = base + (size_t)(5 + c0) * 361 + hw;
            float xv[CPB];
            #pragma unroll
            for (int u = 0; u < CPB; u++) xv[u] = p0[u * 361];
            float cf = sigmoidf_(cr);
            float xt = thr_for(cf);
            unsigned ib = (unsigned)((hw * NUMA + a) * NUMC + c0);
            #pragma unroll
            for (int u = 0; u < CPB; u++)
                if (xv[u] > xt) LEMIT(sigmoidf_(xv[u]) * cf, ib + (unsigned)u);
        }
    } else {
        const float* tip; int vHW, v, candOff;
        if (cx < 4) { tip = t1; vHW = 361;  v = (cx - 2) * 256 + tid; candOff = 86640; }
        else        { tip = t2; vHW = 1444; v = (cx - 4) * 256 + tid; candOff = 433200; }
        if (v < vHW) {
            const f32x4* bp = (const f32x4*)(tip + (size_t)(b * 255 + a * 85) * (size_t)(vHW * 4));
            f32x4 cv = bp[(size_t)4 * vHW + v];
            const f32x4* p0 = bp + (size_t)(5 + c0) * vHW + v;
            f32x4 sv[CPB];
            #pragma unroll
            for (int u = 0; u < CPB; u++) sv[u] = p0[(size_t)u * vHW];
            float cf0 = sigmoidf_(cv[0]), cf1 = sigmoidf_(cv[1]);
            float cf2 = sigmoidf_(cv[2]), cf3 = sigmoidf_(cv[3]);
            float xt0 = thr_for(cf0), xt1 = thr_for(cf1);
            float xt2 = thr_for(cf2), xt3 = thr_for(cf3);
            unsigned ib0 = (unsigned)(candOff + (v * 4 * NUMA + a) * NUMC + c0);
            #pragma unroll
            for (int u = 0; u < CPB; u++) {
                unsigned ib = ib0 + (unsigned)u;
                if (sv[u][0] > xt0) LEMIT(sigmoidf_(sv[u][0]) * cf0, ib);
                if (sv[u][1] > xt1) LEMIT(sigmoidf_(sv[u][1]) * cf1, ib + 240);
                if (sv[u][2] > xt2) LEMIT(sigmoidf_(sv[u][2]) * cf2, ib + 480);
                if (sv[u][3] > xt3) LEMIT(sigmoidf_(sv[u][3]) * cf3, ib + 720);
            }
        }
    }
    #undef LEMIT

    __syncthreads();
    if (tid == 0) {
        unsigned c = lcnt;
        if (c > LBUF) {
            atomicOr(&ccnt[b], 0x80000000u);
            lbase = 0xFFFFFFFFu;
        } else {
            lbase = atomicAdd(&ccnt[b], c);
        }
    }
    __syncthreads();
    unsigned c = uminu(lcnt, (unsigned)LBUF);
    unsigned basep = lbase;
    if (basep != 0xFFFFFFFFu) {
        for (unsigned i = tid; i < c; i += 256) {
            unsigned p = basep + i;
            if (p < CAP) {
                ckey[(size_t)b * CAP + p] = lkey[i];
                cidx[(size_t)b * CAP + p] = lidx[i];
            }
        }
    }
    unsigned* gh = histN + b * NBIN;
    for (int i = tid; i < NBIN; i += 256) {
        unsigned v2 = lh[i];
        if (v2) atomicAdd(&gh[i], v2);
    }
}

// ---------------- wave-parallel rank select over an LDS histogram ----------
__device__ __forceinline__ void wave_select(const unsigned* h, int nbins, unsigned rank,
                                            unsigned* resv, int tid)
{
    if (tid >= 64) return;
    const int lane = tid;
    const int cs = nbins >> 6;
    unsigned v = 0;
    for (int k = 0; k < cs; k++) {
        int off = (k + lane) & (cs - 1);
        v += h[lane * cs + off];
    }
    unsigned S = v;
    #pragma unroll
    for (int o = 1; o < 64; o <<= 1) {
        unsigned t = (unsigned)__shfl_down((int)S, o);
        if (lane + o < 64) S += t;
    }
    unsigned long long bm = __ballot(S >= rank);
    if (bm == 0ull) bm = 1ull;
    int C = 63 - __builtin_clzll(bm);
    unsigned SC = (unsigned)__builtin_amdgcn_readlane((int)S, C);
    unsigned vC = (unsigned)__builtin_amdgcn_readlane((int)v, C);
    unsigned rem = rank - (SC - vC);
    unsigned w = (lane < cs) ? h[C * cs + lane] : 0u;
    unsigned T = w;
    #pragma unroll
    for (int o = 1; o < 64; o <<= 1) {
        unsigned t = (unsigned)__shfl_down((int)T, o);
        if (lane + o < 64) T += t;
    }
    unsigned long long bm2 = __ballot((T >= rem) && (lane < cs));
    if (bm2 == 0ull) bm2 = 1ull;
    int B = 63 - __builtin_clzll(bm2);
    unsigned TB = (unsigned)__builtin_amdgcn_readlane((int)T, B);
    unsigned wB = (unsigned)__builtin_amdgcn_readlane((int)w, B);
    if (lane == 0) {
        resv[0] = (unsigned)(C * cs + B);
        resv[1] = rem - (TB - wB);
    }
}

// ---------------- topk_sel: (cold fb) + select + bitonic + decode ----------
// R12: DIRECT fast path. The prefiltered set (bins >= Bf) provably contains
// the exact top-400 (bins monotone in key; >=400 keys in bins >= Bf; equal
// keys share a bin). When pfCnt <= 512: skip radix rounds 1-3, the K400
// compaction and tie handling entirely -- copy pk/pi into the 512 sort
// slots (pad key=0 sorts last) and bitonic-sort by (key desc, idx asc);
// ranks 0..399 are exactly the previous selection and order. pfCnt > 512:
// unchanged radix path.
__global__ __launch_bounds__(1024) void topk_sel(
        const float* __restrict__ t0, const float* __restrict__ t1,
        const float* __restrict__ t2,
        const float* __restrict__ anc0, const float* __restrict__ anc1,
        const float* __restrict__ anc2,
        const unsigned* __restrict__ histN, const unsigned* __restrict__ ccnt,
        unsigned* __restrict__ ckey, unsigned* __restrict__ cidx,
        float* __restrict__ dX1, float* __restrict__ dY1,
        float* __restrict__ dX2, float* __restrict__ dY2,
        float* __restrict__ dSC, unsigned* __restrict__ dCID)
{
    const int b = blockIdx.x;
    const int tid = threadIdx.x;
    const int T = 1024;

    __shared__ unsigned hist[4096];
    __shared__ unsigned resv[2];
    __shared__ unsigned selk[512], seli[512];
    __shared__ unsigned eqi[EQCAP];
    __shared__ unsigned pk[PFCAP], pi[PFCAP];
    __shared__ unsigned cnts[3];   // 0: sel count, 1: eq count, 2: prefilter count
    __shared__ unsigned fcnt;

    unsigned* ck = ckey + (size_t)b * CAP;
    unsigned* ci = cidx + (size_t)b * CAP;
    unsigned nraw = ccnt[b];
    unsigned kbase = KEY0;
    unsigned SH = 13;              // matches score_main's (key-KEY0)>>13

    bool cold = !(nraw >= KTOP && nraw <= CAP);
    if (cold) {
        // ---- COLD fallback: static 0.45 cut invalid for this image ----
        const int NPOS = 3 * (361 + 1444 + 5776);   // 22743 (anchor,pos) pairs
        for (int i = tid; i < 2048; i += T) hist[i] = 0;
        if (tid == 0) fcnt = 0;
        __syncthreads();
        // pass 1: histogram all 1.8M scores by key >> 19
        for (int p = tid; p < NPOS; p += T) {
            const float* tip; int HW, pp;
            if (p < 1083)      { tip = t0; HW = 361;  pp = p; }
            else if (p < 5415) { tip = t1; HW = 1444; pp = p - 1083; }
            else               { tip = t2; HW = 5776; pp = p - 5415; }
            int a = pp / HW, hwl = pp - a * HW;
            const float* base = tip + (size_t)(b * 255 + a * 85) * HW;
            float cf = sigmoidf_(base[4 * HW + hwl]);
            for (int u = 0; u < NUMC; u++) {
                float sc = sigmoidf_(base[(size_t)(5 + u) * HW + hwl]) * cf;
                atomicAdd(&hist[__float_as_uint(sc) >> 19], 1u);
            }
        }
        __syncthreads();
        wave_select(hist, 2048, KTOP, resv, tid);
        __syncthreads();
        unsigned cutkey = resv[0] << 19;
        __syncthreads();
        // pass 2: recompact with the exact bin cut (global ckey/cidx)
        for (int p = tid; p < NPOS; p += T) {
            const float* tip; int HW, pp, candOff;
            if (p < 1083)      { tip = t0; HW = 361;  pp = p;        candOff = 0; }
            else if (p < 5415) { tip = t1; HW = 1444; pp = p - 1083; candOff = 86640; }
            else               { tip = t2; HW = 5776; pp = p - 5415; candOff = 433200; }
            int a = pp / HW, hwl = pp - a * HW;
            const float* base = tip + (size_t)(b * 255 + a * 85) * HW;
            float cf = sigmoidf_(base[4 * HW + hwl]);
            unsigned ib0 = (unsigned)(candOff + (hwl * NUMA + a) * NUMC);
            for (int u = 0; u < NUMC; u++) {
                float sc = sigmoidf_(base[(size_t)(5 + u) * HW + hwl]) * cf;
                unsigned key = __float_as_uint(sc);
                if (key >= cutkey) {
                    unsigned pos = atomicAdd(&fcnt, 1u);
                    if (pos < CAP) { ck[pos] = key; ci[pos] = ib0 + (unsigned)u; }
                }
            }
        }
        __syncthreads();
        nraw = fcnt;
        kbase = cutkey;
        unsigned span = (KEYTOP - kbase) + 1u;
        SH = 0;
        while ((span >> SH) > 2047u) SH++;
    }
    unsigned n = uminu(nraw, (unsigned)CAP);

    // ---- Phase A: coarse hist. Warm: load prebuilt histN. Cold: build. ----
    if (cold) {
        for (int i = tid; i < 2048; i += T) hist[i] = 0;
        __syncthreads();
        unsigned n4 = n >> 2;
        const uint4* ck4 = (const uint4*)ck;
        for (unsigned i = tid; i < n4; i += T) {
            uint4 k = ck4[i];
            atomicAdd(&hist[(k.x - kbase) >> SH], 1u);
            atomicAdd(&hist[(k.y - kbase) >> SH], 1u);
            atomicAdd(&hist[(k.z - kbase) >> SH], 1u);
            atomicAdd(&hist[(k.w - kbase) >> SH], 1u);
        }
        for (unsigned i = (n4 << 2) + tid; i < n; i += T)
            atomicAdd(&hist[(ck[i] - kbase) >> SH], 1u);
    } else {
        for (int i = tid; i < 2048; i += T) hist[i] = histN[b * NBIN + i];
    }
    __syncthreads();
    wave_select(hist, 2048, KTOP, resv, tid);
    __syncthreads();
    unsigned Bf = resv[0];            // rank-400 floor bin
    __syncthreads();

    // ---- Phase B: compact bins >= Bf into LDS (pk/pi) ----
    if (tid == 0) { cnts[0] = 0; cnts[1] = 0; cnts[2] = 0; }
    __syncthreads();
    for (unsigned i = tid; i < n; i += T) {
        unsigned k = ck[i];
        if (((k - kbase) >> SH) >= Bf) {
            unsigned q = atomicAdd(&cnts[2], 1u);
            if (q < (unsigned)PFCAP) { pk[q] = k; pi[q] = ci[i]; }
        }
    }
    __syncthreads();
    unsigned pfCnt = cnts[2];
    bool useP = (pfCnt <= (unsigned)PFCAP);   // else: global-rescan fallback
    unsigned m = useP ? pfCnt : n;
    bool direct = useP && (pfCnt <= 512u);    // R12 fast path (common case)

    if (direct) {
        // ---- DIRECT: prefiltered set == superset of top-400; just sort ----
        for (int i = tid; i < 512; i += T) { selk[i] = 0u; seli[i] = 0xFFFFFFFFu; }
        __syncthreads();
        for (unsigned i = tid; i < pfCnt; i += T) { selk[i] = pk[i]; seli[i] = pi[i]; }
        __syncthreads();
    } else {
        // ---- Round 1: bits [30:19] over source ----
        for (int i = tid; i < 4096; i += T) hist[i] = 0;
        __syncthreads();
        for (unsigned i = tid; i < m; i += T) {
            unsigned k = useP ? pk[i] : ck[i];
            atomicAdd(&hist[k >> 19], 1u);
        }
        __syncthreads();
        wave_select(hist, 4096, KTOP, resv, tid);
        __syncthreads();
        unsigned b1 = resv[0], r2 = resv[1];
        __syncthreads();

        // ---- Round 2: bits [18:7] within bin b1 ----
        for (int i = tid; i < 4096; i += T) hist[i] = 0;
        __syncthreads();
        for (unsigned i = tid; i < m; i += T) {
            unsigned k = useP ? pk[i] : ck[i];
            if ((k >> 19) == b1) atomicAdd(&hist[(k >> 7) & 0xFFFu], 1u);
        }
        __syncthreads();
        wave_select(hist, 4096, r2, resv, tid);
        __syncthreads();
        unsigned b2 = resv[0], r3 = resv[1];
        __syncthreads();

        // ---- Round 3: bits [6:0] ----
        for (int i = tid; i < 128; i += T) hist[i] = 0;
        __syncthreads();
        unsigned pref = (b1 << 12) | b2;
        for (unsigned i = tid; i < m; i += T) {
            unsigned k = useP ? pk[i] : ck[i];
            if ((k >> 7) == pref) atomicAdd(&hist[k & 127u], 1u);
        }
        __syncthreads();
        wave_select(hist, 128, r3, resv, tid);
        __syncthreads();
        unsigned b3 = resv[0], needEq = resv[1];
        unsigned K400 = (b1 << 19) | (b2 << 7) | b3;
        __syncthreads();

        // ---- compaction from source ----
        for (int i = tid; i < 512; i += T) { selk[i] = 0u; seli[i] = 0xFFFFFFFFu; }
        for (int i = tid; i < EQCAP; i += T) eqi[i] = 0xFFFFFFFFu;
        __syncthreads();
        for (unsigned i = tid; i < m; i += T) {
            unsigned k = useP ? pk[i] : ck[i];
            if (k > K400) {
                unsigned idx = useP ? pi[i] : ci[i];
                unsigned p = atomicAdd(&cnts[0], 1u);
                if (p < 512u) { selk[p] = k; seli[p] = idx; }
            } else if (k == K400) {
                unsigned idx = useP ? pi[i] : ci[i];
                unsigned q = atomicAdd(&cnts[1], 1u);
                if (q < (unsigned)EQCAP) eqi[q] = idx;
            }
        }
        __syncthreads();
        unsigned selCnt = uminu(cnts[0], (unsigned)KTOP);
        unsigned eqN   = uminu(cnts[1], (unsigned)EQCAP);

        // ---- tie list: only sort if we must pick a strict subset ----
        if (eqN > needEq) {
            int P2 = 1; while ((unsigned)P2 < eqN) P2 <<= 1;
            for (int k2 = 2; k2 <= P2; k2 <<= 1) {
                for (int j = k2 >> 1; j > 0; j >>= 1) {
                    __syncthreads();
                    for (int i = tid; i < P2; i += T) {
                        int ixj = i ^ j;
                        if (ixj > i && ixj < P2) {
                            unsigned va = eqi[i], vb = eqi[ixj];
                            bool up = ((i & k2) == 0);
                            if (up ? (va > vb) : (va < vb)) { eqi[i] = vb; eqi[ixj] = va; }
                        }
                    }
                }
            }
            __syncthreads();
        }
        for (unsigned t2v = tid; t2v < needEq; t2v += T) {
            unsigned p = selCnt + t2v;
            if (p < KTOP) { selk[p] = K400; seli[p] = eqi[t2v]; }
        }
        __syncthreads();
    }

    // ---- bitonic sort 512 by (key desc, idx asc); j<64 passes in-wave ----
    for (int k2 = 2; k2 <= 512; k2 <<= 1) {
        int j = k2 >> 1;
        for (; j >= 64; j >>= 1) {
            __syncthreads();
            if (tid < 512) {
                int i = tid, ixj = i ^ j;
                if (ixj > i) {
                    unsigned ka = selk[i], kb = selk[ixj], ia = seli[i], ib = seli[ixj];
                    bool before = (ka > kb) || (ka == kb && ia < ib);
                    bool up = ((i & k2) == 0);
                    if (up ? !before : before) {
                        selk[i] = kb; selk[ixj] = ka; seli[i] = ib; seli[ixj] = ia;
                    }
                }
            }
        }
        __syncthreads();
        if (tid < 512) {
            for (; j > 0; j >>= 1) {
                int i = tid, ixj = i ^ j;
                if (ixj > i) {
                    unsigned ka = selk[i], kb = selk[ixj], ia = seli[i], ib = seli[ixj];
                    bool before = (ka > kb) || (ka == kb && ia < ib);
                    bool up = ((i & k2) == 0);
                    if (up ? !before : before) {
                        selk[i] = kb; selk[ixj] = ka; seli[i] = ib; seli[ixj] = ia;
                    }
                }
            }
        }
    }
    __syncthreads();

    // ---- gather + on-the-fly box decode; write det arrays (coalesced) ----
    if (tid < KTOP) {
        unsigned idx = seli[tid];
        int o = b * KTOP + tid;
        if (idx == 0xFFFFFFFFu) {          // impossible on valid data; no OOB
            dX1[o] = -1.f; dY1[o] = -1.f; dX2[o] = -1.f; dY2[o] = -1.f;
            dSC[o] = __uint_as_float(selk[tid]); dCID[o] = 0u;
        } else {
            const float* tip; const float* anc; int HW, W, candOff; float strideF;
            if (idx < 86640u)       { tip = t0; anc = anc0; HW = 361;  W = 19; strideF = 32.f; candOff = 0; }
            else if (idx < 433200u) { tip = t1; anc = anc1; HW = 1444; W = 38; strideF = 16.f; candOff = 86640; }
            else                    { tip = t2; anc = anc2; HW = 5776; W = 76; strideF = 8.f;  candOff = 433200; }
            unsigned local = idx - (unsigned)candOff;
            int cls = (int)(local % NUMC);
            int nn  = (int)(local / NUMC);
            int a = nn % NUMA, hwl = nn / NUMA;
            const float* base = tip + (size_t)(b * 255 + a * 85) * HW + hwl;
            float tx = base[0];
            float ty = base[(size_t)HW];
            float tw = base[(size_t)2 * HW];
            float th = base[(size_t)3 * HW];
            float fx = (float)(hwl % W), fy = (float)(hwl / W);
            float cx = (sigmoidf_(tx) + fx) * strideF;
            float cy = (sigmoidf_(ty) + fy) * strideF;
            float hw_ = expf(tw) * anc[2 * a]     * 0.5f;
            float hh_ = expf(th) * anc[2 * a + 1] * 0.5f;
            dX1[o] = cx - hw_; dY1[o] = cy - hh_;
            dX2[o] = cx + hw_; dY2[o] = cy + hh_;
            dSC[o] = __uint_as_float(selk[tid]);
            dCID[o] = (unsigned)cls;
        }
    }
}

// ---------------- mask: parallel suppression-bitmask build (R7) ------------
// grid (11, 8) = 88 blocks: the O(K^2) IoU phase NEEDS breadth (R3/R6/R8
// all showed -40us when this ran on 8 blocks). Inner j-loop rotated by
// (t + 9w)&63 so the 7 w-groups (j0 = w*64, bank-0-aligned) read 7
// DIFFERENT banks each step; OR-accum is order-free.
__global__ __launch_bounds__(256) void mask_kernel(
        const float* __restrict__ dX1, const float* __restrict__ dY1,
        const float* __restrict__ dX2, const float* __restrict__ dY2,
        const unsigned* __restrict__ dCID, unsigned long long* __restrict__ maskG)
{
    __shared__ float lx1[KTOP], ly1[KTOP], lx2[KTOP], ly2[KTOP];
    __shared__ int lcid[KTOP];
    const int b = blockIdx.y;
    const int tid = threadIdx.x;
    for (int i = tid; i < KTOP; i += 256) {
        int o = b * KTOP + i;
        lx1[i] = dX1[o]; ly1[i] = dY1[o];
        lx2[i] = dX2[o]; ly2[i] = dY2[o];
        lcid[i] = (int)dCID[o];
    }
    __syncthreads();
    int p = blockIdx.x * 256 + tid;
    if (p < NMASK) {
        int i = p / 7, w = p - i * 7;
        float x1i = lx1[i], y1i = ly1[i], x2i = lx2[i], y2i = ly2[i];
        float ai = fmaxf(x2i - x1i, 0.f) * fmaxf(y2i - y1i, 0.f);
        int cidI = lcid[i];
        unsigned long long m = 0ull;
        int j0 = w * 64;
        int rot = (9 * w) & 63;
        for (int t = 0; t < 64; t++) {
            int j = j0 + ((t + rot) & 63);
            if (j >= KTOP || j <= i) continue;
            if (lcid[j] != cidI) continue;
            float iw = fminf(x2i, lx2[j]) - fmaxf(x1i, lx1[j]);
            float ih = fminf(y2i, ly2[j]) - fmaxf(y1i, ly1[j]);
            iw = fmaxf(iw, 0.f); ih = fmaxf(ih, 0.f);
            float inter = iw * ih;
            float aj = fmaxf(lx2[j] - lx1[j], 0.f) * fmaxf(ly2[j] - ly1[j], 0.f);
            float iou = inter / (ai + aj - inter + 1e-12f);
            if (iou > 0.45f) m |= (1ull << (j - j0));
        }
        maskG[(size_t)b * NMASK + p] = m;
    }
}

// ---------------- greedy + output: 8-deep prefetch ring (R7) ---------------
__global__ __launch_bounds__(512) void greedy_kernel(
        const float* __restrict__ dX1, const float* __restrict__ dY1,
        const float* __restrict__ dX2, const float* __restrict__ dY2,
        const float* __restrict__ dSC, const unsigned* __restrict__ dCID,
        const unsigned long long* __restrict__ maskG, float* __restrict__ out)
{
    __shared__ unsigned long long maskL[NMASK];
    __shared__ unsigned long long vkeep[7];
    __shared__ float oid[POST], osc[POST], obb[POST * 4];
    const int b = blockIdx.x;
    const int tid = threadIdx.x;

    for (int i = tid; i < NMASK; i += 512) maskL[i] = maskG[(size_t)b * NMASK + i];
    if (tid < POST) { oid[tid] = -1.f; osc[tid] = -1.f; }
    if (tid < POST * 4) obb[tid] = -1.f;
    __syncthreads();

    if (tid < 64) {
        const int lane = tid;
        unsigned long long keep = 0ull;
        if (lane < 7) keep = (lane == 6) ? 0xFFFFull : ~0ull;
        unsigned long long mb[8];
        #pragma unroll
        for (int k = 0; k < 8; k++)
            mb[k] = (lane < 7) ? maskL[k * 7 + lane] : 0ull;
        for (int ib = 0; ib < KTOP; ib += 8) {
            #pragma unroll
            for (int k = 0; k < 8; k++) {
                int i = ib + k;
                unsigned long long m = mb[k];
                int nf = ib + 8 + k;
                mb[k] = (lane < 7 && nf < KTOP) ? maskL[nf * 7 + lane] : 0ull;
                int w = i >> 6;  // wave-uniform
                unsigned klo = (unsigned)__builtin_amdgcn_readlane((int)(unsigned)(keep & 0xFFFFFFFFull), w);
                unsigned khi = (unsigned)__builtin_amdgcn_readlane((int)(unsigned)(keep >> 32), w);
                unsigned long long kw = ((unsigned long long)khi << 32) | klo;
                if ((kw >> (i & 63)) & 1ull) keep &= ~m;
            }
        }
        if (lane < 7) vkeep[lane] = keep;
    }
    __syncthreads();

    if (tid < KTOP) {
        int w = tid >> 6, bp = tid & 63;
        unsigned long long kw = vkeep[w];
        if ((kw >> bp) & 1ull) {
            int r = 0;
            for (int q = 0; q < w; q++) r += __popcll(vkeep[q]);
            r += __popcll(kw & ((1ull << bp) - 1ull));
            if (r < POST) {
                int o = b * KTOP + tid;
                oid[r] = (float)(int)dCID[o];
                osc[r] = dSC[o];
                obb[r * 4 + 0] = dX1[o];
                obb[r * 4 + 1] = dY1[o];
                obb[r * 4 + 2] = dX2[o];
                obb[r * 4 + 3] = dY2[o];
            }
        }
    }
    __syncthreads();
    if (tid < POST) {
        out[b * POST + tid]       = oid[tid];
        out[800 + b * POST + tid] = osc[tid];
    }
    if (tid < POST * 4) out[1600 + b * POST * 4 + tid] = obb[tid];
}

// ---------------------------------------------------------------------------
extern "C" void kernel_launch(void* const* d_in, const int* in_sizes, int n_in,
                              void* d_out, int out_size, void* d_ws, size_t ws_size,
                              hipStream_t stream)
{
    const float* tip0 = (const float*)d_in[0];
    const float* tip1 = (const float*)d_in[1];
    const float* tip2 = (const float*)d_in[2];
    const float* anc0 = (const float*)d_in[3];
    const float* anc1 = (const float*)d_in[4];
    const float* anc2 = (const float*)d_in[5];
    float* out = (float*)d_out;

    // ws layout (u32 unless noted): histN(8*NBIN) | ccnt(8) | ckey(8*CAP) |
    // cidx(8*CAP) | det 6x3200 f32 | maskG 8*2800 u64
    unsigned* histN = (unsigned*)d_ws;
    unsigned* ccnt  = histN + 8 * NBIN;
    unsigned* ckey  = ccnt + 8;
    unsigned* cidx  = ckey + (size_t)8 * CAP;
    float*    dX1   = (float*)(cidx + (size_t)8 * CAP);
    float*    dY1   = dX1 + 8 * KTOP;
    float*    dX2   = dY1 + 8 * KTOP;
    float*    dY2   = dX2 + 8 * KTOP;
    float*    dSC   = dY2 + 8 * KTOP;
    unsigned* dCID  = (unsigned*)(dSC + 8 * KTOP);
    unsigned long long* maskG = (unsigned long long*)(dCID + 8 * KTOP);

    // zero histN + ccnt in one stream-ordered (graph-capturable) memset
    hipMemsetAsync(histN, 0, (8 * NBIN + 8) * sizeof(unsigned), stream);

    dim3 g(10, 80 / CPB, 24);
    score_main<<<g, 256, 0, stream>>>(tip0, tip1, tip2, histN, ccnt, ckey, cidx);
    topk_sel<<<8, 1024, 0, stream>>>(tip0, tip1, tip2, anc0, anc1, anc2,
                                     histN, ccnt, ckey, cidx,
                                     dX1, dY1, dX2, dY2, dSC, dCID);
    mask_kernel<<<dim3((NMASK + 255) / 256, 8), 256, 0, stream>>>(
        dX1, dY1, dX2, dY2, dCID, maskG);
    greedy_kernel<<<8, 512, 0, stream>>>(dX1, dY1, dX2, dY2, dSC, dCID, maskG, out);
}

// Round 13
// 183.375 us; speedup vs baseline: 1.0685x; 1.0136x over previous
//
#include <hip/hip_runtime.h>
#include <stdint.h>

#define NUMA 3
#define NUMC 80
#define CAP  49152
#define KTOP 400
#define POST 100
#define EQCAP 1024
#define PFCAP 2048
#define KEY0 0x3EE66666u   // __float_as_uint(0.45f): static compact threshold
#define KEYTOP 0x3F800000u // __float_as_uint(1.0f): max possible score key
#define LBUF 1024          // per-block LDS candidate buffer
#define NMASK (KTOP * 7)   // 2800 mask words per image
#define CPB 20             // classes per score_main block

typedef float f32x4 __attribute__((ext_vector_type(4)));

__device__ __forceinline__ float sigmoidf_(float x) { return 1.0f / (1.0f + expf(-x)); }
__device__ __forceinline__ unsigned uminu(unsigned a, unsigned b) { return a < b ? a : b; }

// Conservative raw-logit threshold: x > thr(cf) is NECESSARY for
// sigmoid(x)*cf >= 0.45f (margins 0.449 + 0.01 dwarf float error; the exact
// test still decides membership, so the candidate set is bit-identical).
// cf < 0.45f admits nothing: sc = round(sig*cf) <= cf < 0.45f.
__device__ __forceinline__ float thr_for(float cf) {
    if (!(cf >= 0.45f)) return 3.0e38f;
    float q = 0.449f / cf;             // < 1 guaranteed (cf >= 0.45)
    float r = q / (1.0f - q);
    return logf(r) - 0.01f;
}

// ---------------- main pass: decode + LDS compact (R9 lean form) -----------
// R13: histN hoist reverted (R9 vs R11 A/B isolated it at +2.2us net cost);
// topk_sel rebuilds the coarse hist from the compacted keys (cheap: ~13K
// uint4 loads across 1024 threads). 20 classes per block -> grid (10,4,24)
// = 960 blocks, 20 f32x4 loads in flight per thread. Exactly one global
// atomic per block (R1: per-candidate global atomics serialize 40x).
// Overflow (>LBUF) poisons ccnt -> exact cold-path rebuild.
__global__ __launch_bounds__(256) void score_main(
        const float* __restrict__ t0, const float* __restrict__ t1,
        const float* __restrict__ t2,
        unsigned* __restrict__ ccnt, unsigned* __restrict__ ckey,
        unsigned* __restrict__ cidx)
{
    __shared__ unsigned lkey[LBUF], lidx[LBUF];
    __shared__ unsigned lcnt, lbase;
    const int tid = threadIdx.x;
    if (tid == 0) lcnt = 0;
    __syncthreads();

    const int ba = blockIdx.z;
    const int b = ba / 3, a = ba - 3 * b;
    const int c0 = blockIdx.y * CPB;
    const int cx = blockIdx.x;

    #define LEMIT(SC, IDX) do { \
        unsigned key_ = __float_as_uint(SC); \
        if (key_ >= KEY0) { \
            unsigned pos_ = atomicAdd(&lcnt, 1u); \
            if (pos_ < LBUF) { lkey[pos_] = key_; lidx[pos_] = (IDX); } \
        } \
    } while (0)

    if (cx < 2) {
        const int hw = cx * 256 + tid;
        if (hw < 361) {
            const float* base = t0 + (size_t)(b * 255 + a * 85) * 361;
            float cr = base[4 * 361 + hw];
            const float* p0 = base + (size_t)(5 + c0) * 361 + hw;
            float xv[CPB];
            #pragma unroll
            for (int u = 0; u < CPB; u++) xv[u] = p0[u * 361];
            float cf = sigmoidf_(cr);
            float xt = thr_for(cf);
            unsigned ib = (unsigned)((hw * NUMA + a) * NUMC + c0);
            #pragma unroll
            for (int u = 0; u < CPB; u++)
                if (xv[u] > xt) LEMIT(sigmoidf_(xv[u]) * cf, ib + (unsigned)u);
        }
    } else {
        const float* tip; int vHW, v, candOff;
        if (cx < 4) { tip = t1; vHW = 361;  v = (cx - 2) * 256 + tid; candOff = 86640; }
        else        { tip = t2; vHW = 1444; v = (cx - 4) * 256 + tid; candOff = 433200; }
        if (v < vHW) {
            const f32x4* bp = (const f32x4*)(tip + (size_t)(b * 255 + a * 85) * (size_t)(vHW * 4));
            f32x4 cv = bp[(size_t)4 * vHW + v];
            const f32x4* p0 = bp + (size_t)(5 + c0) * vHW + v;
            f32x4 sv[CPB];
            #pragma unroll
            for (int u = 0; u < CPB; u++) sv[u] = p0[(size_t)u * vHW];
            float cf0 = sigmoidf_(cv[0]), cf1 = sigmoidf_(cv[1]);
            float cf2 = sigmoidf_(cv[2]), cf3 = sigmoidf_(cv[3]);
            float xt0 = thr_for(cf0), xt1 = thr_for(cf1);
            float xt2 = thr_for(cf2), xt3 = thr_for(cf3);
            unsigned ib0 = (unsigned)(candOff + (v * 4 * NUMA + a) * NUMC + c0);
            #pragma unroll
            for (int u = 0; u < CPB; u++) {
                unsigned ib = ib0 + (unsigned)u;
                if (sv[u][0] > xt0) LEMIT(sigmoidf_(sv[u][0]) * cf0, ib);
                if (sv[u][1] > xt1) LEMIT(sigmoidf_(sv[u][1]) * cf1, ib + 240);
                if (sv[u][2] > xt2) LEMIT(sigmoidf_(sv[u][2]) * cf2, ib + 480);
                if (sv[u][3] > xt3) LEMIT(sigmoidf_(sv[u][3]) * cf3, ib + 720);
            }
        }
    }
    #undef LEMIT

    __syncthreads();
    if (tid == 0) {
        unsigned c = lcnt;
        if (c > LBUF) {
            atomicOr(&ccnt[b], 0x80000000u);
            lbase = 0xFFFFFFFFu;
        } else {
            lbase = atomicAdd(&ccnt[b], c);
        }
    }
    __syncthreads();
    unsigned c = uminu(lcnt, (unsigned)LBUF);
    unsigned basep = lbase;
    if (basep != 0xFFFFFFFFu) {
        for (unsigned i = tid; i < c; i += 256) {
            unsigned p = basep + i;
            if (p < CAP) {
                ckey[(size_t)b * CAP + p] = lkey[i];
                cidx[(size_t)b * CAP + p] = lidx[i];
            }
        }
    }
}

// ---------------- wave-parallel rank select over an LDS histogram ----------
__device__ __forceinline__ void wave_select(const unsigned* h, int nbins, unsigned rank,
                                            unsigned* resv, int tid)
{
    if (tid >= 64) return;
    const int lane = tid;
    const int cs = nbins >> 6;
    unsigned v = 0;
    for (int k = 0; k < cs; k++) {
        int off = (k + lane) & (cs - 1);
        v += h[lane * cs + off];
    }
    unsigned S = v;
    #pragma unroll
    for (int o = 1; o < 64; o <<= 1) {
        unsigned t = (unsigned)__shfl_down((int)S, o);
        if (lane + o < 64) S += t;
    }
    unsigned long long bm = __ballot(S >= rank);
    if (bm == 0ull) bm = 1ull;
    int C = 63 - __builtin_clzll(bm);
    unsigned SC = (unsigned)__builtin_amdgcn_readlane((int)S, C);
    unsigned vC = (unsigned)__builtin_amdgcn_readlane((int)v, C);
    unsigned rem = rank - (SC - vC);
    unsigned w = (lane < cs) ? h[C * cs + lane] : 0u;
    unsigned T = w;
    #pragma unroll
    for (int o = 1; o < 64; o <<= 1) {
        unsigned t = (unsigned)__shfl_down((int)T, o);
        if (lane + o < 64) T += t;
    }
    unsigned long long bm2 = __ballot((T >= rem) && (lane < cs));
    if (bm2 == 0ull) bm2 = 1ull;
    int B = 63 - __builtin_clzll(bm2);
    unsigned TB = (unsigned)__builtin_amdgcn_readlane((int)T, B);
    unsigned wB = (unsigned)__builtin_amdgcn_readlane((int)w, B);
    if (lane == 0) {
        resv[0] = (unsigned)(C * cs + B);
        resv[1] = rem - (TB - wB);
    }
}

// ---------------- topk_sel: (cold fb) + prefilter + direct/radix + decode --
// R13 = R12's direct fast path + R9's in-kernel Phase A scan (histN hoist
// reverted). DIRECT path: the prefiltered set (bins >= Bf) provably
// contains the exact top-400 (bins monotone in key; >=400 keys in bins
// >= Bf; equal keys share a bin). When pfCnt <= 512: skip radix rounds,
// K400 compaction and tie handling; sort directly. pfCnt > 512: radix.
__global__ __launch_bounds__(1024) void topk_sel(
        const float* __restrict__ t0, const float* __restrict__ t1,
        const float* __restrict__ t2,
        const float* __restrict__ anc0, const float* __restrict__ anc1,
        const float* __restrict__ anc2,
        const unsigned* __restrict__ ccnt,
        unsigned* __restrict__ ckey, unsigned* __restrict__ cidx,
        float* __restrict__ dX1, float* __restrict__ dY1,
        float* __restrict__ dX2, float* __restrict__ dY2,
        float* __restrict__ dSC, unsigned* __restrict__ dCID)
{
    const int b = blockIdx.x;
    const int tid = threadIdx.x;
    const int T = 1024;

    __shared__ unsigned hist[4096];
    __shared__ unsigned resv[2];
    __shared__ unsigned selk[512], seli[512];
    __shared__ unsigned eqi[EQCAP];
    __shared__ unsigned pk[PFCAP], pi[PFCAP];
    __shared__ unsigned cnts[3];   // 0: sel count, 1: eq count, 2: prefilter count
    __shared__ unsigned fcnt;

    unsigned* ck = ckey + (size_t)b * CAP;
    unsigned* ci = cidx + (size_t)b * CAP;
    unsigned nraw = ccnt[b];
    unsigned kbase = KEY0;

    bool cold = !(nraw >= KTOP && nraw <= CAP);
    if (cold) {
        // ---- COLD fallback: static 0.45 cut invalid for this image ----
        const int NPOS = 3 * (361 + 1444 + 5776);   // 22743 (anchor,pos) pairs
        for (int i = tid; i < 2048; i += T) hist[i] = 0;
        if (tid == 0) fcnt = 0;
        __syncthreads();
        // pass 1: histogram all 1.8M scores by key >> 19
        for (int p = tid; p < NPOS; p += T) {
            const float* tip; int HW, pp;
            if (p < 1083)      { tip = t0; HW = 361;  pp = p; }
            else if (p < 5415) { tip = t1; HW = 1444; pp = p - 1083; }
            else               { tip = t2; HW = 5776; pp = p - 5415; }
            int a = pp / HW, hwl = pp - a * HW;
            const float* base = tip + (size_t)(b * 255 + a * 85) * HW;
            float cf = sigmoidf_(base[4 * HW + hwl]);
            for (int u = 0; u < NUMC; u++) {
                float sc = sigmoidf_(base[(size_t)(5 + u) * HW + hwl]) * cf;
                atomicAdd(&hist[__float_as_uint(sc) >> 19], 1u);
            }
        }
        __syncthreads();
        wave_select(hist, 2048, KTOP, resv, tid);
        __syncthreads();
        unsigned cutkey = resv[0] << 19;
        __syncthreads();
        // pass 2: recompact with the exact bin cut (global ckey/cidx)
        for (int p = tid; p < NPOS; p += T) {
            const float* tip; int HW, pp, candOff;
            if (p < 1083)      { tip = t0; HW = 361;  pp = p;        candOff = 0; }
            else if (p < 5415) { tip = t1; HW = 1444; pp = p - 1083; candOff = 86640; }
            else               { tip = t2; HW = 5776; pp = p - 5415; candOff = 433200; }
            int a = pp / HW, hwl = pp - a * HW;
            const float* base = tip + (size_t)(b * 255 + a * 85) * HW;
            float cf = sigmoidf_(base[4 * HW + hwl]);
            unsigned ib0 = (unsigned)(candOff + (hwl * NUMA + a) * NUMC);
            for (int u = 0; u < NUMC; u++) {
                float sc = sigmoidf_(base[(size_t)(5 + u) * HW + hwl]) * cf;
                unsigned key = __float_as_uint(sc);
                if (key >= cutkey) {
                    unsigned pos = atomicAdd(&fcnt, 1u);
                    if (pos < CAP) { ck[pos] = key; ci[pos] = ib0 + (unsigned)u; }
                }
            }
        }
        __syncthreads();
        nraw = fcnt;
        kbase = cutkey;
    }
    unsigned n = uminu(nraw, (unsigned)CAP);

    // ---- coarse-bin parameters: monotone shifted binning ----
    unsigned span = (KEYTOP - kbase) + 1u;
    unsigned SH = 0;
    while ((span >> SH) > 2047u) SH++;

    // ---- Phase A: coarse hist over ALL keys (vectorized, spread bins) ----
    for (int i = tid; i < 2048; i += T) hist[i] = 0;
    __syncthreads();
    {
        unsigned n4 = n >> 2;
        const uint4* ck4 = (const uint4*)ck;
        for (unsigned i = tid; i < n4; i += T) {
            uint4 k = ck4[i];
            atomicAdd(&hist[(k.x - kbase) >> SH], 1u);
            atomicAdd(&hist[(k.y - kbase) >> SH], 1u);
            atomicAdd(&hist[(k.z - kbase) >> SH], 1u);
            atomicAdd(&hist[(k.w - kbase) >> SH], 1u);
        }
        for (unsigned i = (n4 << 2) + tid; i < n; i += T)
            atomicAdd(&hist[(ck[i] - kbase) >> SH], 1u);
    }
    __syncthreads();
    wave_select(hist, 2048, KTOP, resv, tid);
    __syncthreads();
    unsigned Bf = resv[0];            // rank-400 floor bin
    __syncthreads();

    // ---- Phase B: compact bins >= Bf into LDS (pk/pi) ----
    if (tid == 0) { cnts[0] = 0; cnts[1] = 0; cnts[2] = 0; }
    __syncthreads();
    for (unsigned i = tid; i < n; i += T) {
        unsigned k = ck[i];
        if (((k - kbase) >> SH) >= Bf) {
            unsigned q = atomicAdd(&cnts[2], 1u);
            if (q < (unsigned)PFCAP) { pk[q] = k; pi[q] = ci[i]; }
        }
    }
    __syncthreads();
    unsigned pfCnt = cnts[2];
    bool useP = (pfCnt <= (unsigned)PFCAP);   // else: global-rescan fallback
    unsigned m = useP ? pfCnt : n;
    bool direct = useP && (pfCnt <= 512u);    // fast path (common case)

    if (direct) {
        // ---- DIRECT: prefiltered set == superset of top-400; just sort ----
        for (int i = tid; i < 512; i += T) { selk[i] = 0u; seli[i] = 0xFFFFFFFFu; }
        __syncthreads();
        for (unsigned i = tid; i < pfCnt; i += T) { selk[i] = pk[i]; seli[i] = pi[i]; }
        __syncthreads();
    } else {
        // ---- Round 1: bits [30:19] over source ----
        for (int i = tid; i < 4096; i += T) hist[i] = 0;
        __syncthreads();
        for (unsigned i = tid; i < m; i += T) {
            unsigned k = useP ? pk[i] : ck[i];
            atomicAdd(&hist[k >> 19], 1u);
        }
        __syncthreads();
        wave_select(hist, 4096, KTOP, resv, tid);
        __syncthreads();
        unsigned b1 = resv[0], r2 = resv[1];
        __syncthreads();

        // ---- Round 2: bits [18:7] within bin b1 ----
        for (int i = tid; i < 4096; i += T) hist[i] = 0;
        __syncthreads();
        for (unsigned i = tid; i < m; i += T) {
            unsigned k = useP ? pk[i] : ck[i];
            if ((k >> 19) == b1) atomicAdd(&hist[(k >> 7) & 0xFFFu], 1u);
        }
        __syncthreads();
        wave_select(hist, 4096, r2, resv, tid);
        __syncthreads();
        unsigned b2 = resv[0], r3 = resv[1];
        __syncthreads();

        // ---- Round 3: bits [6:0] ----
        for (int i = tid; i < 128; i += T) hist[i] = 0;
        __syncthreads();
        unsigned pref = (b1 << 12) | b2;
        for (unsigned i = tid; i < m; i += T) {
            unsigned k = useP ? pk[i] : ck[i];
            if ((k >> 7) == pref) atomicAdd(&hist[k & 127u], 1u);
        }
        __syncthreads();
        wave_select(hist, 128, r3, resv, tid);
        __syncthreads();
        unsigned b3 = resv[0], needEq = resv[1];
        unsigned K400 = (b1 << 19) | (b2 << 7) | b3;
        __syncthreads();

        // ---- compaction from source ----
        for (int i = tid; i < 512; i += T) { selk[i] = 0u; seli[i] = 0xFFFFFFFFu; }
        for (int i = tid; i < EQCAP; i += T) eqi[i] = 0xFFFFFFFFu;
        __syncthreads();
        for (unsigned i = tid; i < m; i += T) {
            unsigned k = useP ? pk[i] : ck[i];
            if (k > K400) {
                unsigned idx = useP ? pi[i] : ci[i];
                unsigned p = atomicAdd(&cnts[0], 1u);
                if (p < 512u) { selk[p] = k; seli[p] = idx; }
            } else if (k == K400) {
                unsigned idx = useP ? pi[i] : ci[i];
                unsigned q = atomicAdd(&cnts[1], 1u);
                if (q < (unsigned)EQCAP) eqi[q] = idx;
            }
        }
        __syncthreads();
        unsigned selCnt = uminu(cnts[0], (unsigned)KTOP);
        unsigned eqN   = uminu(cnts[1], (unsigned)EQCAP);

        // ---- tie list: only sort if we must pick a strict subset ----
        if (eqN > needEq) {
            int P2 = 1; while ((unsigned)P2 < eqN) P2 <<= 1;
            for (int k2 = 2; k2 <= P2; k2 <<= 1) {
                for (int j = k2 >> 1; j > 0; j >>= 1) {
                    __syncthreads();
                    for (int i = tid; i < P2; i += T) {
                        int ixj = i ^ j;
                        if (ixj > i && ixj < P2) {
                            unsigned va = eqi[i], vb = eqi[ixj];
                            bool up = ((i & k2) == 0);
                            if (up ? (va > vb) : (va < vb)) { eqi[i] = vb; eqi[ixj] = va; }
                        }
                    }
                }
            }
            __syncthreads();
        }
        for (unsigned t2v = tid; t2v < needEq; t2v += T) {
            unsigned p = selCnt + t2v;
            if (p < KTOP) { selk[p] = K400; seli[p] = eqi[t2v]; }
        }
        __syncthreads();
    }

    // ---- bitonic sort 512 by (key desc, idx asc); j<64 passes in-wave ----
    for (int k2 = 2; k2 <= 512; k2 <<= 1) {
        int j = k2 >> 1;
        for (; j >= 64; j >>= 1) {
            __syncthreads();
            if (tid < 512) {
                int i = tid, ixj = i ^ j;
                if (ixj > i) {
                    unsigned ka = selk[i], kb = selk[ixj], ia = seli[i], ib = seli[ixj];
                    bool before = (ka > kb) || (ka == kb && ia < ib);
                    bool up = ((i & k2) == 0);
                    if (up ? !before : before) {
                        selk[i] = kb; selk[ixj] = ka; seli[i] = ib; seli[ixj] = ia;
                    }
                }
            }
        }
        __syncthreads();
        if (tid < 512) {
            for (; j > 0; j >>= 1) {
                int i = tid, ixj = i ^ j;
                if (ixj > i) {
                    unsigned ka = selk[i], kb = selk[ixj], ia = seli[i], ib = seli[ixj];
                    bool before = (ka > kb) || (ka == kb && ia < ib);
                    bool up = ((i & k2) == 0);
                    if (up ? !before : before) {
                        selk[i] = kb; selk[ixj] = ka; seli[i] = ib; seli[ixj] = ia;
                    }
                }
            }
        }
    }
    __syncthreads();

    // ---- gather + on-the-fly box decode; write det arrays (coalesced) ----
    if (tid < KTOP) {
        unsigned idx = seli[tid];
        int o = b * KTOP + tid;
        if (idx == 0xFFFFFFFFu) {          // impossible on valid data; no OOB
            dX1[o] = -1.f; dY1[o] = -1.f; dX2[o] = -1.f; dY2[o] = -1.f;
            dSC[o] = __uint_as_float(selk[tid]); dCID[o] = 0u;
        } else {
            const float* tip; const float* anc; int HW, W, candOff; float strideF;
            if (idx < 86640u)       { tip = t0; anc = anc0; HW = 361;  W = 19; strideF = 32.f; candOff = 0; }
            else if (idx < 433200u) { tip = t1; anc = anc1; HW = 1444; W = 38; strideF = 16.f; candOff = 86640; }
            else                    { tip = t2; anc = anc2; HW = 5776; W = 76; strideF = 8.f;  candOff = 433200; }
            unsigned local = idx - (unsigned)candOff;
            int cls = (int)(local % NUMC);
            int nn  = (int)(local / NUMC);
            int a = nn % NUMA, hwl = nn / NUMA;
            const float* base = tip + (size_t)(b * 255 + a * 85) * HW + hwl;
            float tx = base[0];
            float ty = base[(size_t)HW];
            float tw = base[(size_t)2 * HW];
            float th = base[(size_t)3 * HW];
            float fx = (float)(hwl % W), fy = (float)(hwl / W);
            float cx = (sigmoidf_(tx) + fx) * strideF;
            float cy = (sigmoidf_(ty) + fy) * strideF;
            float hw_ = expf(tw) * anc[2 * a]     * 0.5f;
            float hh_ = expf(th) * anc[2 * a + 1] * 0.5f;
            dX1[o] = cx - hw_; dY1[o] = cy - hh_;
            dX2[o] = cx + hw_; dY2[o] = cy + hh_;
            dSC[o] = __uint_as_float(selk[tid]);
            dCID[o] = (unsigned)cls;
        }
    }
}

// ---------------- mask: parallel suppression-bitmask build (R7) ------------
// grid (11, 8) = 88 blocks: the O(K^2) IoU phase NEEDS breadth (R3/R6/R8
// all showed -40us when this ran on 8 blocks). Inner j-loop rotated by
// (t + 9w)&63 so the 7 w-groups (j0 = w*64, bank-0-aligned) read 7
// DIFFERENT banks each step; OR-accum is order-free.
__global__ __launch_bounds__(256) void mask_kernel(
        const float* __restrict__ dX1, const float* __restrict__ dY1,
        const float* __restrict__ dX2, const float* __restrict__ dY2,
        const unsigned* __restrict__ dCID, unsigned long long* __restrict__ maskG)
{
    __shared__ float lx1[KTOP], ly1[KTOP], lx2[KTOP], ly2[KTOP];
    __shared__ int lcid[KTOP];
    const int b = blockIdx.y;
    const int tid = threadIdx.x;
    for (int i = tid; i < KTOP; i += 256) {
        int o = b * KTOP + i;
        lx1[i] = dX1[o]; ly1[i] = dY1[o];
        lx2[i] = dX2[o]; ly2[i] = dY2[o];
        lcid[i] = (int)dCID[o];
    }
    __syncthreads();
    int p = blockIdx.x * 256 + tid;
    if (p < NMASK) {
        int i = p / 7, w = p - i * 7;
        float x1i = lx1[i], y1i = ly1[i], x2i = lx2[i], y2i = ly2[i];
        float ai = fmaxf(x2i - x1i, 0.f) * fmaxf(y2i - y1i, 0.f);
        int cidI = lcid[i];
        unsigned long long m = 0ull;
        int j0 = w * 64;
        int rot = (9 * w) & 63;
        for (int t = 0; t < 64; t++) {
            int j = j0 + ((t + rot) & 63);
            if (j >= KTOP || j <= i) continue;
            if (lcid[j] != cidI) continue;
            float iw = fminf(x2i, lx2[j]) - fmaxf(x1i, lx1[j]);
            float ih = fminf(y2i, ly2[j]) - fmaxf(y1i, ly1[j]);
            iw = fmaxf(iw, 0.f); ih = fmaxf(ih, 0.f);
            float inter = iw * ih;
            float aj = fmaxf(lx2[j] - lx1[j], 0.f) * fmaxf(ly2[j] - ly1[j], 0.f);
            float iou = inter / (ai + aj - inter + 1e-12f);
            if (iou > 0.45f) m |= (1ull << (j - j0));
        }
        maskG[(size_t)b * NMASK + p] = m;
    }
}

// ---------------- greedy + output: 8-deep prefetch ring (R7) ---------------
__global__ __launch_bounds__(512) void greedy_kernel(
        const float* __restrict__ dX1, const float* __restrict__ dY1,
        const float* __restrict__ dX2, const float* __restrict__ dY2,
        const float* __restrict__ dSC, const unsigned* __restrict__ dCID,
        const unsigned long long* __restrict__ maskG, float* __restrict__ out)
{
    __shared__ unsigned long long maskL[NMASK];
    __shared__ unsigned long long vkeep[7];
    __shared__ float oid[POST], osc[POST], obb[POST * 4];
    const int b = blockIdx.x;
    const int tid = threadIdx.x;

    for (int i = tid; i < NMASK; i += 512) maskL[i] = maskG[(size_t)b * NMASK + i];
    if (tid < POST) { oid[tid] = -1.f; osc[tid] = -1.f; }
    if (tid < POST * 4) obb[tid] = -1.f;
    __syncthreads();

    if (tid < 64) {
        const int lane = tid;
        unsigned long long keep = 0ull;
        if (lane < 7) keep = (lane == 6) ? 0xFFFFull : ~0ull;
        unsigned long long mb[8];
        #pragma unroll
        for (int k = 0; k < 8; k++)
            mb[k] = (lane < 7) ? maskL[k * 7 + lane] : 0ull;
        for (int ib = 0; ib < KTOP; ib += 8) {
            #pragma unroll
            for (int k = 0; k < 8; k++) {
                int i = ib + k;
                unsigned long long m = mb[k];
                int nf = ib + 8 + k;
                mb[k] = (lane < 7 && nf < KTOP) ? maskL[nf * 7 + lane] : 0ull;
                int w = i >> 6;  // wave-uniform
                unsigned klo = (unsigned)__builtin_amdgcn_readlane((int)(unsigned)(keep & 0xFFFFFFFFull), w);
                unsigned khi = (unsigned)__builtin_amdgcn_readlane((int)(unsigned)(keep >> 32), w);
                unsigned long long kw = ((unsigned long long)khi << 32) | klo;
                if ((kw >> (i & 63)) & 1ull) keep &= ~m;
            }
        }
        if (lane < 7) vkeep[lane] = keep;
    }
    __syncthreads();

    if (tid < KTOP) {
        int w = tid >> 6, bp = tid & 63;
        unsigned long long kw = vkeep[w];
        if ((kw >> bp) & 1ull) {
            int r = 0;
            for (int q = 0; q < w; q++) r += __popcll(vkeep[q]);
            r += __popcll(kw & ((1ull << bp) - 1ull));
            if (r < POST) {
                int o = b * KTOP + tid;
                oid[r] = (float)(int)dCID[o];
                osc[r] = dSC[o];
                obb[r * 4 + 0] = dX1[o];
                obb[r * 4 + 1] = dY1[o];
                obb[r * 4 + 2] = dX2[o];
                obb[r * 4 + 3] = dY2[o];
            }
        }
    }
    __syncthreads();
    if (tid < POST) {
        out[b * POST + tid]       = oid[tid];
        out[800 + b * POST + tid] = osc[tid];
    }
    if (tid < POST * 4) out[1600 + b * POST * 4 + tid] = obb[tid];
}

// ---------------------------------------------------------------------------
extern "C" void kernel_launch(void* const* d_in, const int* in_sizes, int n_in,
                              void* d_out, int out_size, void* d_ws, size_t ws_size,
                              hipStream_t stream)
{
    const float* tip0 = (const float*)d_in[0];
    const float* tip1 = (const float*)d_in[1];
    const float* tip2 = (const float*)d_in[2];
    const float* anc0 = (const float*)d_in[3];
    const float* anc1 = (const float*)d_in[4];
    const float* anc2 = (const float*)d_in[5];
    float* out = (float*)d_out;

    // ws layout (u32 unless noted): ccnt(8) | ckey(8*CAP) | cidx(8*CAP) |
    // det 6x3200 f32 | maskG 8*2800 u64   (histN retired in R13)
    unsigned* ccnt = (unsigned*)d_ws;
    unsigned* ckey = ccnt + 8;
    unsigned* cidx = ckey + (size_t)8 * CAP;
    float*    dX1  = (float*)(cidx + (size_t)8 * CAP);
    float*    dY1  = dX1 + 8 * KTOP;
    float*    dX2  = dY1 + 8 * KTOP;
    float*    dY2  = dX2 + 8 * KTOP;
    float*    dSC  = dY2 + 8 * KTOP;
    unsigned* dCID = (unsigned*)(dSC + 8 * KTOP);
    unsigned long long* maskG = (unsigned long long*)(dCID + 8 * KTOP);

    // stream-ordered (graph-capturable) zero of the 8 image counters
    hipMemsetAsync(ccnt, 0, 8 * sizeof(unsigned), stream);

    dim3 g(10, 80 / CPB, 24);
    score_main<<<g, 256, 0, stream>>>(tip0, tip1, tip2, ccnt, ckey, cidx);
    topk_sel<<<8, 1024, 0, stream>>>(tip0, tip1, tip2, anc0, anc1, anc2,
                                     ccnt, ckey, cidx,
                                     dX1, dY1, dX2, dY2, dSC, dCID);
    mask_kernel<<<dim3((NMASK + 255) / 256, 8), 256, 0, stream>>>(
        dX1, dY1, dX2, dY2, dCID, maskG);
    greedy_kernel<<<8, 512, 0, stream>>>(dX1, dY1, dX2, dY2, dSC, dCID, maskG, out);
}